// Round 18
// baseline (501.723 us; speedup 1.0000x reference)
//
#include <hip/hip_runtime.h>
#include <hip/hip_bf16.h>
#include <math.h>

typedef _Float16 f16;
typedef f16 f16x8 __attribute__((ext_vector_type(8)));
typedef f16 f16x4 __attribute__((ext_vector_type(4)));
typedef float f32x16 __attribute__((ext_vector_type(16)));

// ws layout (f32 slot offsets), fast path:
//   Af16 f16[26214400] @ 0            (13107200 slots)  [b][400pos][256ci]
//   Wf16 f16[5308416]  @ 13107200     (2654208 slots)   [81tap][256co][256ci]
//   Wr   f16[1474560]  @ 15761408     (737280 slots)    routing W in f16
//   partial f32 ks*2359296 @ 16498688  layout [k][m][co]
//   vbuf f32 40960 @ 16498688 + ks*2359296
//   u  f32[2359296] @ 0        (overlays Af16 after conv2)
//   h2 f32[262144]  @ 13107200 (overlays Wf16 after conv2)
//
// LESSONS: (R9-R11) forcing 3-min-waves via launch_bounds spilled the acc ->
// use LDS size to unlock occupancy instead. (R12/R14) grid balance matters.
// (R13) async global_load_lds ring + counted vmcnt: conflicts 0, no spill.
// (R15) routing: 2 samples/block, f16 uh/cl, f16x8 W loads.
// (R18) conv2 ring-2 (48KB LDS) -> 3 blocks/CU; ks=10 (720 blocks, one round).

// ------- fused conv1 + weight-prep launch: grid (17,256) --------------------------
__global__ __launch_bounds__(256) void conv1_kernel(
    const float* __restrict__ x, const float* __restrict__ w,
    const float* __restrict__ bias, f16* __restrict__ outh,
    float* __restrict__ outf, int mode,
    const float* __restrict__ w2, f16* __restrict__ Wf,
    const float* __restrict__ W, f16* __restrict__ Wr)
{
    __shared__ float smem[5184];
    const int t = threadIdx.x;

    if (blockIdx.x == 16) {
        // ---- weight prep path ----
        const int co = blockIdx.y;
        for (int chunk = 0; chunk < 4; ++chunk) {
            const int ci0 = chunk * 64;
            for (int i = t; i < 5184; i += 256)
                smem[i] = w2[(size_t)co * 20736 + ci0 * 81 + i];
            __syncthreads();
            const int ci = t & 63;
            for (int tap = t >> 6; tap < 81; tap += 4)
                Wf[((size_t)tap * 256 + co) * 256 + ci0 + ci] =
                    (f16)smem[ci * 81 + tap];
            __syncthreads();
        }
        const int base = co * 5760;
        for (int i = t; i < 5760; i += 256) Wr[base + i] = (f16)W[base + i];
        return;
    }

    // ---- conv1 path ----
    float* xs = smem;            // 784
    float* wt = smem + 784;      // 1296
    float* bs = smem + 2080;     // 16
    const int b = blockIdx.y;
    const int cg = blockIdx.x;

    for (int i = t; i < 784; i += 256) xs[i] = x[b * 784 + i];
    for (int i = t; i < 1296; i += 256) {
        int k = i >> 4, cc = i & 15;
        wt[i] = w[(cg * 16 + cc) * 81 + k];
    }
    if (t < 16) bs[t] = bias[cg * 16 + t];
    __syncthreads();

    if (t >= 200) return;
    const int pos = t * 2;
    const int oy = pos / 20, ox = pos % 20;
    float4 A0[4], A1[4];
    #pragma unroll
    for (int g = 0; g < 4; ++g) { A0[g] = make_float4(0,0,0,0); A1[g] = make_float4(0,0,0,0); }

    for (int ky = 0; ky < 9; ++ky) {
        const float* xr = &xs[(oy + ky) * 28 + ox];
        #pragma unroll
        for (int kx = 0; kx < 9; ++kx) {
            float x0 = xr[kx], x1 = xr[kx + 1];
            const float4* wp = (const float4*)&wt[(ky * 9 + kx) << 4];
            #pragma unroll
            for (int g = 0; g < 4; ++g) {
                float4 wv = wp[g];
                A0[g].x = fmaf(x0, wv.x, A0[g].x); A0[g].y = fmaf(x0, wv.y, A0[g].y);
                A0[g].z = fmaf(x0, wv.z, A0[g].z); A0[g].w = fmaf(x0, wv.w, A0[g].w);
                A1[g].x = fmaf(x1, wv.x, A1[g].x); A1[g].y = fmaf(x1, wv.y, A1[g].y);
                A1[g].z = fmaf(x1, wv.z, A1[g].z); A1[g].w = fmaf(x1, wv.w, A1[g].w);
            }
        }
    }

    float va[16], vb[16];
    #pragma unroll
    for (int g = 0; g < 4; ++g) {
        va[g*4+0] = fmaxf(A0[g].x + bs[g*4+0], 0.f);
        va[g*4+1] = fmaxf(A0[g].y + bs[g*4+1], 0.f);
        va[g*4+2] = fmaxf(A0[g].z + bs[g*4+2], 0.f);
        va[g*4+3] = fmaxf(A0[g].w + bs[g*4+3], 0.f);
        vb[g*4+0] = fmaxf(A1[g].x + bs[g*4+0], 0.f);
        vb[g*4+1] = fmaxf(A1[g].y + bs[g*4+1], 0.f);
        vb[g*4+2] = fmaxf(A1[g].z + bs[g*4+2], 0.f);
        vb[g*4+3] = fmaxf(A1[g].w + bs[g*4+3], 0.f);
    }

    if (mode == 0) {
        size_t base0 = ((size_t)b * 400 + pos) * 256 + cg * 16;
        f16x8 H;
        #pragma unroll
        for (int q = 0; q < 8; ++q) H[q] = (f16)va[q];
        *(f16x8*)(outh + base0) = H;
        #pragma unroll
        for (int q = 0; q < 8; ++q) H[q] = (f16)va[8+q];
        *(f16x8*)(outh + base0 + 8) = H;
        size_t base1 = base0 + 256;
        #pragma unroll
        for (int q = 0; q < 8; ++q) H[q] = (f16)vb[q];
        *(f16x8*)(outh + base1) = H;
        #pragma unroll
        for (int q = 0; q < 8; ++q) H[q] = (f16)vb[8+q];
        *(f16x8*)(outh + base1 + 8) = H;
    } else {
        #pragma unroll
        for (int q = 0; q < 16; ++q) {
            size_t base = (size_t)(b * 256 + cg * 16 + q) * 400 + pos;
            outf[base] = va[q]; outf[base + 1] = vb[q];
        }
    }
}

// ------- conv2: async global->LDS, ring-2 (48KB -> 3 blocks/CU), ks=10 -------------
#define GLOAD16(GSRC, LDST) \
    __builtin_amdgcn_global_load_lds( \
        (const __attribute__((address_space(1))) void*)(GSRC), \
        (__attribute__((address_space(3))) void*)(LDST), 16, 0, 0)

__global__ __launch_bounds__(256, 2) void conv2_async(
    const f16* __restrict__ A, const f16* __restrict__ B,
    float* __restrict__ partial, int nslice, int spk, int nwg)
{
    const int cpx = nwg >> 3;
    const int wg = (blockIdx.x & 7) * cpx + (blockIdx.x >> 3);
    const int mblk = wg / nslice;
    const int kslice = wg % nslice;

    const int t = threadIdx.x;
    const int lane = t & 63, w = t >> 6;     // 4 waves
    const int wm = w >> 1, wn = w & 1;

    __shared__ f16 sA2[2][4096];   // 16 KB
    __shared__ f16 sB2[2][8192];   // 32 KB  -> total 48 KB, 3 blocks/CU

    const f16* aBase[2];
    #pragma unroll
    for (int q = 0; q < 2; ++q) {
        int m = mblk * 128 + q * 64 + lane;
        int b_ = m / 36, s_ = m % 36;
        aBase[q] = A + b_ * 102400 + ((s_ / 6) * 40 + (s_ % 6) * 2) * 256 + w * 8;
    }
    const f16* bBase[4];
    #pragma unroll
    for (int q = 0; q < 4; ++q)
        bBase[q] = B + (q * 64 + lane) * 256 + w * 8;

    const int g0 = kslice * spk;
    const int len = min(spk, 648 - g0);

    auto issue = [&](int gstep, int buf) {
        const int tap = gstep >> 3;
        const int kc = (gstep & 7) << 5;
        const int ky = tap / 9, kx = tap - ky * 9;
        const int ao = (ky * 20 + kx) * 256 + kc;
        const int bo = tap * 65536 + kc;
        f16* la = &sA2[buf][w * 1024];
        f16* lb = &sB2[buf][w * 2048];
        GLOAD16(aBase[0] + ao, la);
        GLOAD16(aBase[1] + ao, la + 512);
        GLOAD16(bBase[0] + bo, lb);
        GLOAD16(bBase[1] + bo, lb + 512);
        GLOAD16(bBase[2] + bo, lb + 1024);
        GLOAD16(bBase[3] + bo, lb + 1536);
    };

    const int kh = lane >> 5;
    const int rArow = wm * 64 + (lane & 31);
    const int rBrow = wn * 128 + (lane & 31);
    int offA[2], offB[2];
    #pragma unroll
    for (int h = 0; h < 2; ++h) {
        offA[h] = ((h * 2 + kh) << 11) + rArow * 16;
        offB[h] = ((h * 2 + kh) << 12) + rBrow * 16;
    }

    f32x16 acc00 = {}, acc01 = {}, acc02 = {}, acc03 = {};
    f32x16 acc10 = {}, acc11 = {}, acc12 = {}, acc13 = {};

    issue(g0, 0);

    for (int s = 0; s < len; ++s) {
        const int buf = s & 1;
        // drain this step's loads (issued 1 full step ago -> latency covered);
        // barrier guarantees all waves finished computing buf (s-1)&1, so the
        // issue below may safely overwrite it.
        asm volatile("s_waitcnt vmcnt(0)" ::: "memory");
        __builtin_amdgcn_s_barrier();
        asm volatile("" ::: "memory");
        if (s + 1 < len) issue(g0 + s + 1, (s + 1) & 1);

        const char* baseA = (const char*)sA2 + buf * 8192;
        const char* baseB = (const char*)sB2 + buf * 16384;
        #pragma unroll
        for (int h = 0; h < 2; ++h) {
            f16x8 a0 = *(const f16x8*)(baseA + offA[h]);
            f16x8 a1 = *(const f16x8*)(baseA + offA[h] + 512);
            f16x8 b0 = *(const f16x8*)(baseB + offB[h]);
            f16x8 b1 = *(const f16x8*)(baseB + offB[h] + 512);
            f16x8 b2 = *(const f16x8*)(baseB + offB[h] + 1024);
            f16x8 b3 = *(const f16x8*)(baseB + offB[h] + 1536);
            acc00 = __builtin_amdgcn_mfma_f32_32x32x16_f16(a0, b0, acc00, 0, 0, 0);
            acc01 = __builtin_amdgcn_mfma_f32_32x32x16_f16(a0, b1, acc01, 0, 0, 0);
            acc02 = __builtin_amdgcn_mfma_f32_32x32x16_f16(a0, b2, acc02, 0, 0, 0);
            acc03 = __builtin_amdgcn_mfma_f32_32x32x16_f16(a0, b3, acc03, 0, 0, 0);
            acc10 = __builtin_amdgcn_mfma_f32_32x32x16_f16(a1, b0, acc10, 0, 0, 0);
            acc11 = __builtin_amdgcn_mfma_f32_32x32x16_f16(a1, b1, acc11, 0, 0, 0);
            acc12 = __builtin_amdgcn_mfma_f32_32x32x16_f16(a1, b2, acc12, 0, 0, 0);
            acc13 = __builtin_amdgcn_mfma_f32_32x32x16_f16(a1, b3, acc13, 0, 0, 0);
        }
    }

    float* pp = partial + (size_t)kslice * 2359296;
    const int colb = wn * 128 + (lane & 31);
    const int rowb = mblk * 128 + wm * 64 + 4 * (lane >> 5);
    #pragma unroll
    for (int a = 0; a < 2; ++a) {
        #pragma unroll
        for (int nf = 0; nf < 4; ++nf) {
            const f32x16 v = (a == 0)
                ? (nf == 0 ? acc00 : nf == 1 ? acc01 : nf == 2 ? acc02 : acc03)
                : (nf == 0 ? acc10 : nf == 1 ? acc11 : nf == 2 ? acc12 : acc13);
            const int col = colb + nf * 32;
            const int rb = rowb + a * 32;
            #pragma unroll
            for (int r = 0; r < 16; ++r) {
                int row = rb + (r & 3) + 8 * (r >> 2);
                pp[(size_t)row * 256 + col] = v[r];
            }
        }
    }
}

// ------- reduce: 512 threads; partial[k][m][co] + bias+relu+squash -> u --------------
__global__ __launch_bounds__(512) void reduce_kernel(
    const float* __restrict__ partial, const float* __restrict__ bias,
    float* __restrict__ u, int ks)
{
    const int b = blockIdx.x, t = threadIdx.x;
    __shared__ float ld[36 * 260];
    const int cog = t & 63;
    const int srow = t >> 6;
    const float4 bv = *(const float4*)(bias + cog * 4);
    #pragma unroll
    for (int q = 0; q < 5; ++q) {
        const int s = srow + q * 8;
        if (s < 36) {
            const size_t idx = ((size_t)(b * 36 + s)) * 256 + cog * 4;
            float a0 = bv.x, a1 = bv.y, a2 = bv.z, a3 = bv.w;
            for (int k = 0; k < ks; ++k) {
                float4 p = *(const float4*)(partial + (size_t)k * 2359296 + idx);
                a0 += p.x; a1 += p.y; a2 += p.z; a3 += p.w;
            }
            float4 a = make_float4(fmaxf(a0, 0.f), fmaxf(a1, 0.f),
                                   fmaxf(a2, 0.f), fmaxf(a3, 0.f));
            *(float4*)&ld[s * 260 + cog * 4] = a;
        }
    }
    __syncthreads();
    for (int n = t; n < 1152; n += 512) {
        const int f0 = n * 8;
        float vals[8]; float sq = 0.f;
        int co = f0 / 36;
        int si = f0 - co * 36;
        #pragma unroll
        for (int d = 0; d < 8; ++d) {
            float v = ld[si * 260 + co];
            vals[d] = v; sq += v * v;
            if (++si == 36) { si = 0; ++co; }
        }
        float scale = (sq / (1.f + sq)) / sqrtf(sq + 1e-8f);
        #pragma unroll
        for (int d = 0; d < 8; ++d) u[(size_t)b * 9216 + f0 + d] = vals[d] * scale;
    }
}

// ---------------- OLD fallback conv2 (fp32) + squash ----------------
#define C2_CHUNK 2
__global__ __launch_bounds__(384) void conv2_kernel(
    const float* __restrict__ in, const float* __restrict__ w,
    const float* __restrict__ bias, float* __restrict__ out)
{
    const int bg = blockIdx.y;
    const int ct = blockIdx.x;
    const int t = threadIdx.x;

    __shared__ float wl[C2_CHUNK][81][64];
    __shared__ float il[C2_CHUNK][4][20][24];

    const int cg = t & 15;
    const int slot = t >> 4;
    const int bb = slot / 6;
    const int oy = slot % 6;

    float4 acc[6];
    #pragma unroll
    for (int i = 0; i < 6; ++i) acc[i] = make_float4(0,0,0,0);

    for (int cc0 = 0; cc0 < 256; cc0 += C2_CHUNK) {
        for (int idx = t; idx < C2_CHUNK * 5184; idx += 384) {
            int ci = idx / 5184;
            int r = idx - ci * 5184;
            int kk = r >> 6;
            int co = r & 63;
            wl[ci][kk][co] = w[(size_t)(ct * 64 + co) * 20736 + (cc0 + ci) * 81 + kk];
        }
        for (int idx = t; idx < C2_CHUNK * 1600; idx += 384) {
            int ci = idx / 1600;
            int r = idx - ci * 1600;
            int bb2 = r / 400;
            int p = r - bb2 * 400;
            int y = p / 20;
            int xx = p - y * 20;
            il[ci][bb2][y][(xx & 1) * 12 + (xx >> 1)] =
                in[(size_t)((bg * 4 + bb2) * 256 + cc0 + ci) * 400 + p];
        }
        __syncthreads();

        #pragma unroll
        for (int ci = 0; ci < C2_CHUNK; ++ci) {
            for (int ky = 0; ky < 9; ++ky) {
                const int y = oy * 2 + ky;
                const float4* rowp = (const float4*)&il[ci][bb][y][0];
                float a[24];
                #pragma unroll
                for (int q = 0; q < 6; ++q) *(((float4*)a) + q) = rowp[q];
                #pragma unroll
                for (int kx = 0; kx < 9; ++kx) {
                    const int k = ky * 9 + kx;
                    float4 wv = *(const float4*)&wl[ci][k][cg * 4];
                    const int base = (kx & 1) ? (12 + (kx >> 1)) : (kx >> 1);
                    #pragma unroll
                    for (int ox = 0; ox < 6; ++ox) {
                        float av = a[base + ox];
                        acc[ox].x = fmaf(av, wv.x, acc[ox].x);
                        acc[ox].y = fmaf(av, wv.y, acc[ox].y);
                        acc[ox].z = fmaf(av, wv.z, acc[ox].z);
                        acc[ox].w = fmaf(av, wv.w, acc[ox].w);
                    }
                }
            }
        }
        __syncthreads();
    }

    const int b = bg * 4 + bb;
    const int c0 = ct * 64 + cg * 4;
    float4 bv = *(const float4*)&bias[c0];
    #pragma unroll
    for (int ox = 0; ox < 6; ++ox) {
        int sdx = oy * 6 + ox;
        size_t ob = (size_t)b * 9216 + sdx;
        out[ob + (size_t)(c0 + 0) * 36] = fmaxf(acc[ox].x + bv.x, 0.f);
        out[ob + (size_t)(c0 + 1) * 36] = fmaxf(acc[ox].y + bv.y, 0.f);
        out[ob + (size_t)(c0 + 2) * 36] = fmaxf(acc[ox].z + bv.z, 0.f);
        out[ob + (size_t)(c0 + 3) * 36] = fmaxf(acc[ox].w + bv.w, 0.f);
    }
}

__global__ __launch_bounds__(256) void squash_kernel(float* __restrict__ h)
{
    const int cap = blockIdx.x * 256 + threadIdx.x;
    float4* p = (float4*)(h + (size_t)cap * 8);
    float4 v0 = p[0], v1 = p[1];
    float sq = v0.x*v0.x + v0.y*v0.y + v0.z*v0.z + v0.w*v0.w
             + v1.x*v1.x + v1.y*v1.y + v1.z*v1.z + v1.w*v1.w;
    float scale = (sq / (1.f + sq)) / sqrtf(sq + 1e-8f);
    v0.x *= scale; v0.y *= scale; v0.z *= scale; v0.w *= scale;
    v1.x *= scale; v1.y *= scale; v1.z *= scale; v1.w *= scale;
    p[0] = v0; p[1] = v1;
}

// ------- fused u_hat + routing: 2 samples/block share Wc; f16 uh/cl; f16x8 W loads ----
__global__ __launch_bounds__(256) void routing_kernel(
    const float* __restrict__ u, const f16* __restrict__ Wr,
    float* __restrict__ cp_out, float* __restrict__ vbuf)
{
    const int wg = ((blockIdx.x & 7) * 160) + (blockIdx.x >> 3);
    const int c = wg >> 7;
    const int bp = wg & 127;
    const int b0 = bp * 2, b1 = b0 + 1;
    const int t = threadIdx.x;
    const int lane = t & 63, wid = t >> 6;

    __shared__ f16 uhh[2 * 1152 * 16];   // 73728 B
    __shared__ f16 clh[2 * 1152];        // 4608 B
    __shared__ float red[512];           // 2048 B
    __shared__ float rtmp[16];
    __shared__ float vv[2][16];

    {
        const int fg = t & 1;
        const int ng = t >> 1;
        const f16* Wc = Wr + (size_t)c * 147456;
        const float* ub0 = u + (size_t)b0 * 9216;
        const float* ub1 = u + (size_t)b1 * 9216;
        for (int j = 0; j < 9; ++j) {
            const int n = ng + (j << 7);
            const f16* wn = Wc + n * 128 + fg * 8;
            float4 u00 = *(const float4*)(ub0 + n * 8);
            float4 u01 = *(const float4*)(ub0 + n * 8 + 4);
            float4 u10 = *(const float4*)(ub1 + n * 8);
            float4 u11 = *(const float4*)(ub1 + n * 8 + 4);
            float ud0[8] = {u00.x,u00.y,u00.z,u00.w,u01.x,u01.y,u01.z,u01.w};
            float ud1[8] = {u10.x,u10.y,u10.z,u10.w,u11.x,u11.y,u11.z,u11.w};
            float a0[8] = {0,0,0,0,0,0,0,0}, a1[8] = {0,0,0,0,0,0,0,0};
            #pragma unroll
            for (int d = 0; d < 8; ++d) {
                f16x8 w8 = *(const f16x8*)(wn + (d << 4));
                #pragma unroll
                for (int e = 0; e < 8; ++e) {
                    float wf = (float)w8[e];
                    a0[e] = fmaf(ud0[d], wf, a0[e]);
                    a1[e] = fmaf(ud1[d], wf, a1[e]);
                }
            }
            f16x8 h0, h1;
            #pragma unroll
            for (int e = 0; e < 8; ++e) { h0[e] = (f16)a0[e]; h1[e] = (f16)a1[e]; }
            *(f16x8*)&uhh[(n << 4) + (fg << 3)] = h0;
            *(f16x8*)&uhh[18432 + (n << 4) + (fg << 3)] = h1;
        }
    }
    __syncthreads();

    float blr0[5] = {0,0,0,0,0}, blr1[5] = {0,0,0,0,0};
    const int nown = (t < 128) ? 5 : 4;

    for (int it = 0; it < 3; ++it) {
        float m0 = -1e30f, m1 = -1e30f;
        #pragma unroll
        for (int k = 0; k < 5; ++k) if (k < nown) {
            m0 = fmaxf(m0, blr0[k]); m1 = fmaxf(m1, blr1[k]);
        }
        #pragma unroll
        for (int o = 32; o > 0; o >>= 1) {
            m0 = fmaxf(m0, __shfl_xor(m0, o));
            m1 = fmaxf(m1, __shfl_xor(m1, o));
        }
        if (lane == 0) { rtmp[wid] = m0; rtmp[4 + wid] = m1; }
        __syncthreads();
        m0 = fmaxf(fmaxf(rtmp[0], rtmp[1]), fmaxf(rtmp[2], rtmp[3]));
        m1 = fmaxf(fmaxf(rtmp[4], rtmp[5]), fmaxf(rtmp[6], rtmp[7]));

        float s0 = 0.f, s1 = 0.f;
        #pragma unroll
        for (int k = 0; k < 5; ++k) if (k < nown) {
            float e0 = __expf(blr0[k] - m0);
            float e1 = __expf(blr1[k] - m1);
            clh[t + (k << 8)] = (f16)e0;
            clh[1152 + t + (k << 8)] = (f16)e1;
            s0 += e0; s1 += e1;
        }
        #pragma unroll
        for (int o = 32; o > 0; o >>= 1) {
            s0 += __shfl_xor(s0, o);
            s1 += __shfl_xor(s1, o);
        }
        if (lane == 0) { rtmp[8 + wid] = s0; rtmp[12 + wid] = s1; }
        __syncthreads();
        const float inv0 = 1.f / (rtmp[8] + rtmp[9] + rtmp[10] + rtmp[11]);
        const float inv1 = 1.f / (rtmp[12] + rtmp[13] + rtmp[14] + rtmp[15]);

        const int f = t & 15, g = t >> 4;
        float sa0 = 0.f, sa1 = 0.f;
        for (int n = g; n < 1152; n += 16) {
            sa0 = fmaf((float)clh[n], (float)uhh[(n << 4) + f], sa0);
            sa1 = fmaf((float)clh[1152 + n], (float)uhh[18432 + (n << 4) + f], sa1);
        }
        red[(g << 4) + f] = sa0;
        red[256 + (g << 4) + f] = sa1;
        __syncthreads();
        if (t < 32) {
            const int s = t >> 4;
            const int ff = t & 15;
            float sv = 0.f;
            #pragma unroll
            for (int gg = 0; gg < 16; ++gg) sv += red[s * 256 + (gg << 4) + ff];
            sv *= (s == 0) ? inv0 : inv1;
            float sq = sv * sv;
            #pragma unroll
            for (int o = 8; o > 0; o >>= 1) sq += __shfl_xor(sq, o);
            float scale = (sq / (1.f + sq)) / sqrtf(sq + 1e-8f);
            vv[s][ff] = sv * scale;
        }
        __syncthreads();

        if (it < 2) {
            float v0[16], v1[16];
            #pragma unroll
            for (int e = 0; e < 16; ++e) { v0[e] = vv[0][e]; v1[e] = vv[1][e]; }
            #pragma unroll
            for (int k = 0; k < 5; ++k) if (k < nown) {
                const int n = t + (k << 8);
                f16x8 q0 = *(const f16x8*)&uhh[n << 4];
                f16x8 q1 = *(const f16x8*)&uhh[(n << 4) + 8];
                f16x8 r0 = *(const f16x8*)&uhh[18432 + (n << 4)];
                f16x8 r1 = *(const f16x8*)&uhh[18432 + (n << 4) + 8];
                float d0 = 0.f, d1 = 0.f;
                #pragma unroll
                for (int e = 0; e < 8; ++e) {
                    d0 = fmaf((float)q0[e], v0[e], d0);
                    d0 = fmaf((float)q1[e], v0[8 + e], d0);
                    d1 = fmaf((float)r0[e], v1[e], d1);
                    d1 = fmaf((float)r1[e], v1[8 + e], d1);
                }
                blr0[k] += d0; blr1[k] += d1;
            }
        }
    }

    if (t < 32) {
        const int s = t >> 4;
        const int ff = t & 15;
        float v_ = vv[s][ff];
        float s2 = v_ * v_;
        #pragma unroll
        for (int o = 8; o > 0; o >>= 1) s2 += __shfl_xor(s2, o);
        const int b = (s == 0) ? b0 : b1;
        if (ff == 0) cp_out[b * 10 + c] = sqrtf(s2 + 1e-8f);
        vbuf[((b * 10 + c) << 4) + ff] = v_;
    }
}

// ------- dec12: fused argmax+mask + layer1 (LDS) + layer2 GEMM ----------------------
__global__ __launch_bounds__(256) void dec12_kernel(
    const float* __restrict__ cp, const float* __restrict__ vbuf,
    const float* __restrict__ W1, const float* __restrict__ B1,
    const float* __restrict__ W2, const float* __restrict__ B2,
    float* __restrict__ h2)
{
    const int ot = blockIdx.x, bt = blockIdx.y, t = threadIdx.x;
    __shared__ float h1s[16][516];   // 33KB, padded
    __shared__ float r16s[16][16];
    __shared__ int idxs[16];

    if (t < 16) {
        const int b = bt * 16 + t;
        float best = cp[b * 10];
        int idx = 0;
        #pragma unroll
        for (int cc = 1; cc < 10; ++cc) {
            float p = cp[b * 10 + cc];
            if (p > best) { best = p; idx = cc; }
        }
        idxs[t] = idx;
    }
    __syncthreads();
    {
        const int bb = t >> 4, f = t & 15;
        const int b = bt * 16 + bb;
        r16s[bb][f] = vbuf[((b * 10 + idxs[bb]) << 4) + f];
    }
    __syncthreads();

    {
        const int bb = t >> 4, tg = t & 15;
        const float* w = W1 + (size_t)idxs[bb] * 8192;
        float r[16];
        #pragma unroll
        for (int k = 0; k < 16; ++k) r[k] = r16s[bb][k];
        for (int j = tg; j < 512; j += 16) {
            float a = B1[j];
            #pragma unroll
            for (int k = 0; k < 16; ++k) a = fmaf(r[k], w[k * 512 + j], a);
            h1s[bb][j] = fmaxf(a, 0.f);
        }
    }
    __syncthreads();

    {
        const int bb = t >> 4;
        const int o = ot * 64 + (t & 15) * 4;
        float4 bv = *(const float4*)(B2 + o);
        float a0 = bv.x, a1 = bv.y, a2 = bv.z, a3 = bv.w;
        #pragma unroll 4
        for (int k = 0; k < 512; ++k) {
            float hv = h1s[bb][k];
            float4 w0 = *(const float4*)(W2 + (size_t)k * 1024 + o);
            a0 = fmaf(hv, w0.x, a0); a1 = fmaf(hv, w0.y, a1);
            a2 = fmaf(hv, w0.z, a2); a3 = fmaf(hv, w0.w, a3);
        }
        float* hw = h2 + (size_t)(bt * 16 + bb) * 1024 + o;
        hw[0] = fmaxf(a0, 0.f); hw[1] = fmaxf(a1, 0.f);
        hw[2] = fmaxf(a2, 0.f); hw[3] = fmaxf(a3, 0.f);
    }
}

// ------- dec3: grid (13,32) = 416 blocks; 8 batches x 64 outs per block -------------
__global__ __launch_bounds__(256) void dec3_kernel(
    const float* __restrict__ h2, const float* __restrict__ W3,
    const float* __restrict__ B3, float* __restrict__ out)
{
    const int ot = blockIdx.x, bt = blockIdx.y, t = threadIdx.x;
    const int bb = bt * 8 + (t >> 5);
    const int o = ot * 64 + (t & 31) * 2;
    if (o >= 784) return;

    float a0 = B3[o], a1 = B3[o + 1];
    const float* hr = h2 + (size_t)bb * 1024;
    #pragma unroll 4
    for (int k = 0; k < 1024; ++k) {
        float hv = hr[k];
        const float* wp = W3 + (size_t)k * 784 + o;
        a0 = fmaf(hv, wp[0], a0);
        a1 = fmaf(hv, wp[1], a1);
    }
    float* ow = out + (size_t)bb * 784 + o;
    ow[0] = 1.f / (1.f + expf(-a0));
    ow[1] = 1.f / (1.f + expf(-a1));
}

extern "C" void kernel_launch(void* const* d_in, const int* in_sizes, int n_in,
                              void* d_out, int out_size, void* d_ws, size_t ws_size,
                              hipStream_t stream) {
    const float* x   = (const float*)d_in[0];
    const float* w1  = (const float*)d_in[1];
    const float* b1  = (const float*)d_in[2];
    const float* w2  = (const float*)d_in[3];
    const float* b2  = (const float*)d_in[4];
    const float* W   = (const float*)d_in[5];
    const float* dw1 = (const float*)d_in[6];
    const float* db1 = (const float*)d_in[7];
    const float* dw2 = (const float*)d_in[8];
    const float* db2 = (const float*)d_in[9];
    const float* dw3 = (const float*)d_in[10];
    const float* db3 = (const float*)d_in[11];

    float* ws   = (float*)d_ws;
    float* outp = (float*)d_out;

    const size_t avail = ws_size / 4;   // f32 slots
    // ks=10 -> 720 blocks, one co-resident round at 3 blocks/CU (48KB LDS conv2)
    int ks = 0;
    if      (avail >= 16498688ull + 10*2359296ull + 40960ull) ks = 10;
    else if (avail >= 16498688ull +  8*2359296ull + 40960ull) ks = 8;
    else if (avail >= 16498688ull +  7*2359296ull + 40960ull) ks = 7;
    else if (avail >= 16498688ull +  6*2359296ull + 40960ull) ks = 6;
    else if (avail >= 16498688ull +  4*2359296ull + 40960ull) ks = 4;
    else if (avail >= 16498688ull +  2*2359296ull + 40960ull) ks = 2;
    else if (avail >= 16498688ull +  1*2359296ull + 40960ull) ks = 1;

    if (ks > 0) {
        f16* Af = (f16*)ws;
        f16* Wf = (f16*)(ws + 13107200);
        f16* Wr = (f16*)(ws + 15761408);
        float* partial = ws + 16498688;
        float* vbuf = ws + 16498688 + (size_t)ks * 2359296;
        float* u  = ws;                       // overlays Af after conv2
        float* h2 = ws + 13107200;            // overlays Wf after conv2

        const int nwg = 72 * ks;              // 720 for ks=10; % 8 == 0
        const int spk = (648 + ks - 1) / ks;  // 65 for ks=10 (tail slice guarded)
        conv1_kernel<<<dim3(17, 256), 256, 0, stream>>>(x, w1, b1, Af, nullptr, 0,
                                                        w2, Wf, W, Wr);
        conv2_async<<<nwg, 256, 0, stream>>>(Af, Wf, partial, ks, spk, nwg);
        reduce_kernel<<<256, 512, 0, stream>>>(partial, b2, u, ks);
        routing_kernel<<<1280, 256, 0, stream>>>(u, Wr, outp, vbuf);
        dec12_kernel<<<dim3(16, 16), 256, 0, stream>>>(outp, vbuf, dw1, db1, dw2, db2, h2);
        dec3_kernel<<<dim3(13, 32), 256, 0, stream>>>(h2, dw3, db3, outp + 2560);
    } else {
        // fallback: fp32 path (+ f16 routing W at tail of layout)
        float* c1   = ws;                     // 26214400
        float* c2   = c1 + 26214400;          // 2359296
        float* vbuf = c2 + 2359296;           // 40960
        float* h2   = vbuf + 40960;           // 262144
        f16* Wr     = (f16*)(h2 + 262144);    // 737280 slots
        f16* Wfscr  = (f16*)(h2 + 262144 + 368640);
        conv1_kernel<<<dim3(17, 256), 256, 0, stream>>>(x, w1, b1, nullptr, c1, 1,
                                                        w2, Wfscr, W, Wr);
        conv2_kernel<<<dim3(4, 64), 384, 0, stream>>>(c1, w2, b2, c2);
        squash_kernel<<<1152, 256, 0, stream>>>(c2);
        routing_kernel<<<1280, 256, 0, stream>>>(c2, Wr, outp, vbuf);
        dec12_kernel<<<dim3(16, 16), 256, 0, stream>>>(outp, vbuf, dw1, db1, dw2, db2, h2);
        dec3_kernel<<<dim3(13, 32), 256, 0, stream>>>(h2, dw3, db3, outp + 2560);
    }
}

// Round 19
// 439.878 us; speedup vs baseline: 1.1406x; 1.1406x over previous
//
#include <hip/hip_runtime.h>
#include <hip/hip_bf16.h>
#include <math.h>

typedef _Float16 f16;
typedef f16 f16x8 __attribute__((ext_vector_type(8)));
typedef f16 f16x4 __attribute__((ext_vector_type(4)));
typedef float f32x16 __attribute__((ext_vector_type(16)));

// ws layout (f32 slot offsets), fast path:
//   Af16 f16[26214400] @ 0            (13107200 slots)  [b][400pos][256ci]
//   Wf16 f16[5308416]  @ 13107200     (2654208 slots)   [81tap][256co][256ci]
//   Wr   f16[1474560]  @ 15761408     (737280 slots)    routing W in f16
//   partial f32 ks*2359296 @ 16498688  layout [k][m][co]
//   vbuf f32 40960 @ 16498688 + ks*2359296
//   u  f32[2359296] @ 0        (overlays Af16 after conv2)
//   h2 f32[262144]  @ 13107200 (overlays Wf16 after conv2)
//
// LESSONS: (R9-R11) launch_bounds(256,3) spills the 128-reg accumulator ->
// keep (256,2), VGPR ~88-112. (R12/R14) grid balance near-integer blocks/CU.
// (R13/R14) async global_load_lds RING-3 + COUNTED vmcnt(6): conflicts 0.
// (R18) ring-2 + vmcnt(0)-per-step KILLED the pipeline (162->220us): never
// drain vmcnt mid-loop; conv2 @162us is the local optimum of this structure.
// (R15) routing: 2 samples/block, f16 uh/cl, f16x8 W loads.
// (R16/R17) tail: dec12 fusion, dec3 re-grid, wprep inside conv1, wide reduce.

// ------- fused conv1 + weight-prep launch: grid (17,256) --------------------------
__global__ __launch_bounds__(256) void conv1_kernel(
    const float* __restrict__ x, const float* __restrict__ w,
    const float* __restrict__ bias, f16* __restrict__ outh,
    float* __restrict__ outf, int mode,
    const float* __restrict__ w2, f16* __restrict__ Wf,
    const float* __restrict__ W, f16* __restrict__ Wr)
{
    __shared__ float smem[5184];
    const int t = threadIdx.x;

    if (blockIdx.x == 16) {
        // ---- weight prep path ----
        const int co = blockIdx.y;
        for (int chunk = 0; chunk < 4; ++chunk) {
            const int ci0 = chunk * 64;
            for (int i = t; i < 5184; i += 256)
                smem[i] = w2[(size_t)co * 20736 + ci0 * 81 + i];
            __syncthreads();
            const int ci = t & 63;
            for (int tap = t >> 6; tap < 81; tap += 4)
                Wf[((size_t)tap * 256 + co) * 256 + ci0 + ci] =
                    (f16)smem[ci * 81 + tap];
            __syncthreads();
        }
        const int base = co * 5760;
        for (int i = t; i < 5760; i += 256) Wr[base + i] = (f16)W[base + i];
        return;
    }

    // ---- conv1 path ----
    float* xs = smem;            // 784
    float* wt = smem + 784;      // 1296
    float* bs = smem + 2080;     // 16
    const int b = blockIdx.y;
    const int cg = blockIdx.x;

    for (int i = t; i < 784; i += 256) xs[i] = x[b * 784 + i];
    for (int i = t; i < 1296; i += 256) {
        int k = i >> 4, cc = i & 15;
        wt[i] = w[(cg * 16 + cc) * 81 + k];
    }
    if (t < 16) bs[t] = bias[cg * 16 + t];
    __syncthreads();

    if (t >= 200) return;
    const int pos = t * 2;
    const int oy = pos / 20, ox = pos % 20;
    float4 A0[4], A1[4];
    #pragma unroll
    for (int g = 0; g < 4; ++g) { A0[g] = make_float4(0,0,0,0); A1[g] = make_float4(0,0,0,0); }

    for (int ky = 0; ky < 9; ++ky) {
        const float* xr = &xs[(oy + ky) * 28 + ox];
        #pragma unroll
        for (int kx = 0; kx < 9; ++kx) {
            float x0 = xr[kx], x1 = xr[kx + 1];
            const float4* wp = (const float4*)&wt[(ky * 9 + kx) << 4];
            #pragma unroll
            for (int g = 0; g < 4; ++g) {
                float4 wv = wp[g];
                A0[g].x = fmaf(x0, wv.x, A0[g].x); A0[g].y = fmaf(x0, wv.y, A0[g].y);
                A0[g].z = fmaf(x0, wv.z, A0[g].z); A0[g].w = fmaf(x0, wv.w, A0[g].w);
                A1[g].x = fmaf(x1, wv.x, A1[g].x); A1[g].y = fmaf(x1, wv.y, A1[g].y);
                A1[g].z = fmaf(x1, wv.z, A1[g].z); A1[g].w = fmaf(x1, wv.w, A1[g].w);
            }
        }
    }

    float va[16], vb[16];
    #pragma unroll
    for (int g = 0; g < 4; ++g) {
        va[g*4+0] = fmaxf(A0[g].x + bs[g*4+0], 0.f);
        va[g*4+1] = fmaxf(A0[g].y + bs[g*4+1], 0.f);
        va[g*4+2] = fmaxf(A0[g].z + bs[g*4+2], 0.f);
        va[g*4+3] = fmaxf(A0[g].w + bs[g*4+3], 0.f);
        vb[g*4+0] = fmaxf(A1[g].x + bs[g*4+0], 0.f);
        vb[g*4+1] = fmaxf(A1[g].y + bs[g*4+1], 0.f);
        vb[g*4+2] = fmaxf(A1[g].z + bs[g*4+2], 0.f);
        vb[g*4+3] = fmaxf(A1[g].w + bs[g*4+3], 0.f);
    }

    if (mode == 0) {
        size_t base0 = ((size_t)b * 400 + pos) * 256 + cg * 16;
        f16x8 H;
        #pragma unroll
        for (int q = 0; q < 8; ++q) H[q] = (f16)va[q];
        *(f16x8*)(outh + base0) = H;
        #pragma unroll
        for (int q = 0; q < 8; ++q) H[q] = (f16)va[8+q];
        *(f16x8*)(outh + base0 + 8) = H;
        size_t base1 = base0 + 256;
        #pragma unroll
        for (int q = 0; q < 8; ++q) H[q] = (f16)vb[q];
        *(f16x8*)(outh + base1) = H;
        #pragma unroll
        for (int q = 0; q < 8; ++q) H[q] = (f16)vb[8+q];
        *(f16x8*)(outh + base1 + 8) = H;
    } else {
        #pragma unroll
        for (int q = 0; q < 16; ++q) {
            size_t base = (size_t)(b * 256 + cg * 16 + q) * 400 + pos;
            outf[base] = va[q]; outf[base + 1] = vb[q];
        }
    }
}

// ------- conv2: async global->LDS, ring-3, counted vmcnt(6), ks=7 ------------------
#define GLOAD16(GSRC, LDST) \
    __builtin_amdgcn_global_load_lds( \
        (const __attribute__((address_space(1))) void*)(GSRC), \
        (__attribute__((address_space(3))) void*)(LDST), 16, 0, 0)

__global__ __launch_bounds__(256, 2) void conv2_async(
    const f16* __restrict__ A, const f16* __restrict__ B,
    float* __restrict__ partial, int nslice, int spk, int nwg)
{
    const int cpx = nwg >> 3;
    const int wg = (blockIdx.x & 7) * cpx + (blockIdx.x >> 3);
    const int mblk = wg / nslice;
    const int kslice = wg % nslice;

    const int t = threadIdx.x;
    const int lane = t & 63, w = t >> 6;     // 4 waves
    const int wm = w >> 1, wn = w & 1;

    __shared__ f16 sA3[3][4096];   // 24 KB
    __shared__ f16 sB3[3][8192];   // 48 KB

    const f16* aBase[2];
    #pragma unroll
    for (int q = 0; q < 2; ++q) {
        int m = mblk * 128 + q * 64 + lane;
        int b_ = m / 36, s_ = m % 36;
        aBase[q] = A + b_ * 102400 + ((s_ / 6) * 40 + (s_ % 6) * 2) * 256 + w * 8;
    }
    const f16* bBase[4];
    #pragma unroll
    for (int q = 0; q < 4; ++q)
        bBase[q] = B + (q * 64 + lane) * 256 + w * 8;

    const int g0 = kslice * spk;
    const int len = min(spk, 648 - g0);

    auto issue = [&](int gstep, int buf) {
        const int tap = gstep >> 3;
        const int kc = (gstep & 7) << 5;
        const int ky = tap / 9, kx = tap - ky * 9;
        const int ao = (ky * 20 + kx) * 256 + kc;
        const int bo = tap * 65536 + kc;
        f16* la = &sA3[buf][w * 1024];
        f16* lb = &sB3[buf][w * 2048];
        GLOAD16(aBase[0] + ao, la);
        GLOAD16(aBase[1] + ao, la + 512);
        GLOAD16(bBase[0] + bo, lb);
        GLOAD16(bBase[1] + bo, lb + 512);
        GLOAD16(bBase[2] + bo, lb + 1024);
        GLOAD16(bBase[3] + bo, lb + 1536);
    };

    const int kh = lane >> 5;
    const int rArow = wm * 64 + (lane & 31);
    const int rBrow = wn * 128 + (lane & 31);
    int offA[2], offB[2];
    #pragma unroll
    for (int h = 0; h < 2; ++h) {
        offA[h] = ((h * 2 + kh) << 11) + rArow * 16;
        offB[h] = ((h * 2 + kh) << 12) + rBrow * 16;
    }

    f32x16 acc00 = {}, acc01 = {}, acc02 = {}, acc03 = {};
    f32x16 acc10 = {}, acc11 = {}, acc12 = {}, acc13 = {};

    issue(g0, 0);
    if (len > 1) issue(g0 + 1, 1);

    for (int s = 0; s < len; ++s) {
        const int buf = s % 3;
        if (s + 1 < len) { asm volatile("s_waitcnt vmcnt(6)" ::: "memory"); }
        else             { asm volatile("s_waitcnt vmcnt(0)" ::: "memory"); }
        __builtin_amdgcn_s_barrier();
        asm volatile("" ::: "memory");
        if (s + 2 < len) issue(g0 + s + 2, (s + 2) % 3);

        const char* baseA = (const char*)sA3 + buf * 8192;
        const char* baseB = (const char*)sB3 + buf * 16384;
        #pragma unroll
        for (int h = 0; h < 2; ++h) {
            f16x8 a0 = *(const f16x8*)(baseA + offA[h]);
            f16x8 a1 = *(const f16x8*)(baseA + offA[h] + 512);
            f16x8 b0 = *(const f16x8*)(baseB + offB[h]);
            f16x8 b1 = *(const f16x8*)(baseB + offB[h] + 512);
            f16x8 b2 = *(const f16x8*)(baseB + offB[h] + 1024);
            f16x8 b3 = *(const f16x8*)(baseB + offB[h] + 1536);
            acc00 = __builtin_amdgcn_mfma_f32_32x32x16_f16(a0, b0, acc00, 0, 0, 0);
            acc01 = __builtin_amdgcn_mfma_f32_32x32x16_f16(a0, b1, acc01, 0, 0, 0);
            acc02 = __builtin_amdgcn_mfma_f32_32x32x16_f16(a0, b2, acc02, 0, 0, 0);
            acc03 = __builtin_amdgcn_mfma_f32_32x32x16_f16(a0, b3, acc03, 0, 0, 0);
            acc10 = __builtin_amdgcn_mfma_f32_32x32x16_f16(a1, b0, acc10, 0, 0, 0);
            acc11 = __builtin_amdgcn_mfma_f32_32x32x16_f16(a1, b1, acc11, 0, 0, 0);
            acc12 = __builtin_amdgcn_mfma_f32_32x32x16_f16(a1, b2, acc12, 0, 0, 0);
            acc13 = __builtin_amdgcn_mfma_f32_32x32x16_f16(a1, b3, acc13, 0, 0, 0);
        }
    }

    float* pp = partial + (size_t)kslice * 2359296;
    const int colb = wn * 128 + (lane & 31);
    const int rowb = mblk * 128 + wm * 64 + 4 * (lane >> 5);
    #pragma unroll
    for (int a = 0; a < 2; ++a) {
        #pragma unroll
        for (int nf = 0; nf < 4; ++nf) {
            const f32x16 v = (a == 0)
                ? (nf == 0 ? acc00 : nf == 1 ? acc01 : nf == 2 ? acc02 : acc03)
                : (nf == 0 ? acc10 : nf == 1 ? acc11 : nf == 2 ? acc12 : acc13);
            const int col = colb + nf * 32;
            const int rb = rowb + a * 32;
            #pragma unroll
            for (int r = 0; r < 16; ++r) {
                int row = rb + (r & 3) + 8 * (r >> 2);
                pp[(size_t)row * 256 + col] = v[r];
            }
        }
    }
}

// ------- reduce: 512 threads; partial[k][m][co] + bias+relu+squash -> u --------------
__global__ __launch_bounds__(512) void reduce_kernel(
    const float* __restrict__ partial, const float* __restrict__ bias,
    float* __restrict__ u, int ks)
{
    const int b = blockIdx.x, t = threadIdx.x;
    __shared__ float ld[36 * 260];
    const int cog = t & 63;
    const int srow = t >> 6;
    const float4 bv = *(const float4*)(bias + cog * 4);
    #pragma unroll
    for (int q = 0; q < 5; ++q) {
        const int s = srow + q * 8;
        if (s < 36) {
            const size_t idx = ((size_t)(b * 36 + s)) * 256 + cog * 4;
            float a0 = bv.x, a1 = bv.y, a2 = bv.z, a3 = bv.w;
            for (int k = 0; k < ks; ++k) {
                float4 p = *(const float4*)(partial + (size_t)k * 2359296 + idx);
                a0 += p.x; a1 += p.y; a2 += p.z; a3 += p.w;
            }
            float4 a = make_float4(fmaxf(a0, 0.f), fmaxf(a1, 0.f),
                                   fmaxf(a2, 0.f), fmaxf(a3, 0.f));
            *(float4*)&ld[s * 260 + cog * 4] = a;
        }
    }
    __syncthreads();
    for (int n = t; n < 1152; n += 512) {
        const int f0 = n * 8;
        float vals[8]; float sq = 0.f;
        int co = f0 / 36;
        int si = f0 - co * 36;
        #pragma unroll
        for (int d = 0; d < 8; ++d) {
            float v = ld[si * 260 + co];
            vals[d] = v; sq += v * v;
            if (++si == 36) { si = 0; ++co; }
        }
        float scale = (sq / (1.f + sq)) / sqrtf(sq + 1e-8f);
        #pragma unroll
        for (int d = 0; d < 8; ++d) u[(size_t)b * 9216 + f0 + d] = vals[d] * scale;
    }
}

// ---------------- OLD fallback conv2 (fp32) + squash ----------------
#define C2_CHUNK 2
__global__ __launch_bounds__(384) void conv2_kernel(
    const float* __restrict__ in, const float* __restrict__ w,
    const float* __restrict__ bias, float* __restrict__ out)
{
    const int bg = blockIdx.y;
    const int ct = blockIdx.x;
    const int t = threadIdx.x;

    __shared__ float wl[C2_CHUNK][81][64];
    __shared__ float il[C2_CHUNK][4][20][24];

    const int cg = t & 15;
    const int slot = t >> 4;
    const int bb = slot / 6;
    const int oy = slot % 6;

    float4 acc[6];
    #pragma unroll
    for (int i = 0; i < 6; ++i) acc[i] = make_float4(0,0,0,0);

    for (int cc0 = 0; cc0 < 256; cc0 += C2_CHUNK) {
        for (int idx = t; idx < C2_CHUNK * 5184; idx += 384) {
            int ci = idx / 5184;
            int r = idx - ci * 5184;
            int kk = r >> 6;
            int co = r & 63;
            wl[ci][kk][co] = w[(size_t)(ct * 64 + co) * 20736 + (cc0 + ci) * 81 + kk];
        }
        for (int idx = t; idx < C2_CHUNK * 1600; idx += 384) {
            int ci = idx / 1600;
            int r = idx - ci * 1600;
            int bb2 = r / 400;
            int p = r - bb2 * 400;
            int y = p / 20;
            int xx = p - y * 20;
            il[ci][bb2][y][(xx & 1) * 12 + (xx >> 1)] =
                in[(size_t)((bg * 4 + bb2) * 256 + cc0 + ci) * 400 + p];
        }
        __syncthreads();

        #pragma unroll
        for (int ci = 0; ci < C2_CHUNK; ++ci) {
            for (int ky = 0; ky < 9; ++ky) {
                const int y = oy * 2 + ky;
                const float4* rowp = (const float4*)&il[ci][bb][y][0];
                float a[24];
                #pragma unroll
                for (int q = 0; q < 6; ++q) *(((float4*)a) + q) = rowp[q];
                #pragma unroll
                for (int kx = 0; kx < 9; ++kx) {
                    const int k = ky * 9 + kx;
                    float4 wv = *(const float4*)&wl[ci][k][cg * 4];
                    const int base = (kx & 1) ? (12 + (kx >> 1)) : (kx >> 1);
                    #pragma unroll
                    for (int ox = 0; ox < 6; ++ox) {
                        float av = a[base + ox];
                        acc[ox].x = fmaf(av, wv.x, acc[ox].x);
                        acc[ox].y = fmaf(av, wv.y, acc[ox].y);
                        acc[ox].z = fmaf(av, wv.z, acc[ox].z);
                        acc[ox].w = fmaf(av, wv.w, acc[ox].w);
                    }
                }
            }
        }
        __syncthreads();
    }

    const int b = bg * 4 + bb;
    const int c0 = ct * 64 + cg * 4;
    float4 bv = *(const float4*)&bias[c0];
    #pragma unroll
    for (int ox = 0; ox < 6; ++ox) {
        int sdx = oy * 6 + ox;
        size_t ob = (size_t)b * 9216 + sdx;
        out[ob + (size_t)(c0 + 0) * 36] = fmaxf(acc[ox].x + bv.x, 0.f);
        out[ob + (size_t)(c0 + 1) * 36] = fmaxf(acc[ox].y + bv.y, 0.f);
        out[ob + (size_t)(c0 + 2) * 36] = fmaxf(acc[ox].z + bv.z, 0.f);
        out[ob + (size_t)(c0 + 3) * 36] = fmaxf(acc[ox].w + bv.w, 0.f);
    }
}

__global__ __launch_bounds__(256) void squash_kernel(float* __restrict__ h)
{
    const int cap = blockIdx.x * 256 + threadIdx.x;
    float4* p = (float4*)(h + (size_t)cap * 8);
    float4 v0 = p[0], v1 = p[1];
    float sq = v0.x*v0.x + v0.y*v0.y + v0.z*v0.z + v0.w*v0.w
             + v1.x*v1.x + v1.y*v1.y + v1.z*v1.z + v1.w*v1.w;
    float scale = (sq / (1.f + sq)) / sqrtf(sq + 1e-8f);
    v0.x *= scale; v0.y *= scale; v0.z *= scale; v0.w *= scale;
    v1.x *= scale; v1.y *= scale; v1.z *= scale; v1.w *= scale;
    p[0] = v0; p[1] = v1;
}

// ------- fused u_hat + routing: 2 samples/block share Wc; f16 uh/cl; f16x8 W loads ----
__global__ __launch_bounds__(256) void routing_kernel(
    const float* __restrict__ u, const f16* __restrict__ Wr,
    float* __restrict__ cp_out, float* __restrict__ vbuf)
{
    const int wg = ((blockIdx.x & 7) * 160) + (blockIdx.x >> 3);
    const int c = wg >> 7;
    const int bp = wg & 127;
    const int b0 = bp * 2, b1 = b0 + 1;
    const int t = threadIdx.x;
    const int lane = t & 63, wid = t >> 6;

    __shared__ f16 uhh[2 * 1152 * 16];   // 73728 B
    __shared__ f16 clh[2 * 1152];        // 4608 B
    __shared__ float red[512];           // 2048 B
    __shared__ float rtmp[16];
    __shared__ float vv[2][16];

    {
        const int fg = t & 1;
        const int ng = t >> 1;
        const f16* Wc = Wr + (size_t)c * 147456;
        const float* ub0 = u + (size_t)b0 * 9216;
        const float* ub1 = u + (size_t)b1 * 9216;
        for (int j = 0; j < 9; ++j) {
            const int n = ng + (j << 7);
            const f16* wn = Wc + n * 128 + fg * 8;
            float4 u00 = *(const float4*)(ub0 + n * 8);
            float4 u01 = *(const float4*)(ub0 + n * 8 + 4);
            float4 u10 = *(const float4*)(ub1 + n * 8);
            float4 u11 = *(const float4*)(ub1 + n * 8 + 4);
            float ud0[8] = {u00.x,u00.y,u00.z,u00.w,u01.x,u01.y,u01.z,u01.w};
            float ud1[8] = {u10.x,u10.y,u10.z,u10.w,u11.x,u11.y,u11.z,u11.w};
            float a0[8] = {0,0,0,0,0,0,0,0}, a1[8] = {0,0,0,0,0,0,0,0};
            #pragma unroll
            for (int d = 0; d < 8; ++d) {
                f16x8 w8 = *(const f16x8*)(wn + (d << 4));
                #pragma unroll
                for (int e = 0; e < 8; ++e) {
                    float wf = (float)w8[e];
                    a0[e] = fmaf(ud0[d], wf, a0[e]);
                    a1[e] = fmaf(ud1[d], wf, a1[e]);
                }
            }
            f16x8 h0, h1;
            #pragma unroll
            for (int e = 0; e < 8; ++e) { h0[e] = (f16)a0[e]; h1[e] = (f16)a1[e]; }
            *(f16x8*)&uhh[(n << 4) + (fg << 3)] = h0;
            *(f16x8*)&uhh[18432 + (n << 4) + (fg << 3)] = h1;
        }
    }
    __syncthreads();

    float blr0[5] = {0,0,0,0,0}, blr1[5] = {0,0,0,0,0};
    const int nown = (t < 128) ? 5 : 4;

    for (int it = 0; it < 3; ++it) {
        float m0 = -1e30f, m1 = -1e30f;
        #pragma unroll
        for (int k = 0; k < 5; ++k) if (k < nown) {
            m0 = fmaxf(m0, blr0[k]); m1 = fmaxf(m1, blr1[k]);
        }
        #pragma unroll
        for (int o = 32; o > 0; o >>= 1) {
            m0 = fmaxf(m0, __shfl_xor(m0, o));
            m1 = fmaxf(m1, __shfl_xor(m1, o));
        }
        if (lane == 0) { rtmp[wid] = m0; rtmp[4 + wid] = m1; }
        __syncthreads();
        m0 = fmaxf(fmaxf(rtmp[0], rtmp[1]), fmaxf(rtmp[2], rtmp[3]));
        m1 = fmaxf(fmaxf(rtmp[4], rtmp[5]), fmaxf(rtmp[6], rtmp[7]));

        float s0 = 0.f, s1 = 0.f;
        #pragma unroll
        for (int k = 0; k < 5; ++k) if (k < nown) {
            float e0 = __expf(blr0[k] - m0);
            float e1 = __expf(blr1[k] - m1);
            clh[t + (k << 8)] = (f16)e0;
            clh[1152 + t + (k << 8)] = (f16)e1;
            s0 += e0; s1 += e1;
        }
        #pragma unroll
        for (int o = 32; o > 0; o >>= 1) {
            s0 += __shfl_xor(s0, o);
            s1 += __shfl_xor(s1, o);
        }
        if (lane == 0) { rtmp[8 + wid] = s0; rtmp[12 + wid] = s1; }
        __syncthreads();
        const float inv0 = 1.f / (rtmp[8] + rtmp[9] + rtmp[10] + rtmp[11]);
        const float inv1 = 1.f / (rtmp[12] + rtmp[13] + rtmp[14] + rtmp[15]);

        const int f = t & 15, g = t >> 4;
        float sa0 = 0.f, sa1 = 0.f;
        for (int n = g; n < 1152; n += 16) {
            sa0 = fmaf((float)clh[n], (float)uhh[(n << 4) + f], sa0);
            sa1 = fmaf((float)clh[1152 + n], (float)uhh[18432 + (n << 4) + f], sa1);
        }
        red[(g << 4) + f] = sa0;
        red[256 + (g << 4) + f] = sa1;
        __syncthreads();
        if (t < 32) {
            const int s = t >> 4;
            const int ff = t & 15;
            float sv = 0.f;
            #pragma unroll
            for (int gg = 0; gg < 16; ++gg) sv += red[s * 256 + (gg << 4) + ff];
            sv *= (s == 0) ? inv0 : inv1;
            float sq = sv * sv;
            #pragma unroll
            for (int o = 8; o > 0; o >>= 1) sq += __shfl_xor(sq, o);
            float scale = (sq / (1.f + sq)) / sqrtf(sq + 1e-8f);
            vv[s][ff] = sv * scale;
        }
        __syncthreads();

        if (it < 2) {
            float v0[16], v1[16];
            #pragma unroll
            for (int e = 0; e < 16; ++e) { v0[e] = vv[0][e]; v1[e] = vv[1][e]; }
            #pragma unroll
            for (int k = 0; k < 5; ++k) if (k < nown) {
                const int n = t + (k << 8);
                f16x8 q0 = *(const f16x8*)&uhh[n << 4];
                f16x8 q1 = *(const f16x8*)&uhh[(n << 4) + 8];
                f16x8 r0 = *(const f16x8*)&uhh[18432 + (n << 4)];
                f16x8 r1 = *(const f16x8*)&uhh[18432 + (n << 4) + 8];
                float d0 = 0.f, d1 = 0.f;
                #pragma unroll
                for (int e = 0; e < 8; ++e) {
                    d0 = fmaf((float)q0[e], v0[e], d0);
                    d0 = fmaf((float)q1[e], v0[8 + e], d0);
                    d1 = fmaf((float)r0[e], v1[e], d1);
                    d1 = fmaf((float)r1[e], v1[8 + e], d1);
                }
                blr0[k] += d0; blr1[k] += d1;
            }
        }
    }

    if (t < 32) {
        const int s = t >> 4;
        const int ff = t & 15;
        float v_ = vv[s][ff];
        float s2 = v_ * v_;
        #pragma unroll
        for (int o = 8; o > 0; o >>= 1) s2 += __shfl_xor(s2, o);
        const int b = (s == 0) ? b0 : b1;
        if (ff == 0) cp_out[b * 10 + c] = sqrtf(s2 + 1e-8f);
        vbuf[((b * 10 + c) << 4) + ff] = v_;
    }
}

// ------- dec12: fused argmax+mask + layer1 (LDS) + layer2 GEMM ----------------------
__global__ __launch_bounds__(256) void dec12_kernel(
    const float* __restrict__ cp, const float* __restrict__ vbuf,
    const float* __restrict__ W1, const float* __restrict__ B1,
    const float* __restrict__ W2, const float* __restrict__ B2,
    float* __restrict__ h2)
{
    const int ot = blockIdx.x, bt = blockIdx.y, t = threadIdx.x;
    __shared__ float h1s[16][516];   // 33KB, padded
    __shared__ float r16s[16][16];
    __shared__ int idxs[16];

    if (t < 16) {
        const int b = bt * 16 + t;
        float best = cp[b * 10];
        int idx = 0;
        #pragma unroll
        for (int cc = 1; cc < 10; ++cc) {
            float p = cp[b * 10 + cc];
            if (p > best) { best = p; idx = cc; }
        }
        idxs[t] = idx;
    }
    __syncthreads();
    {
        const int bb = t >> 4, f = t & 15;
        const int b = bt * 16 + bb;
        r16s[bb][f] = vbuf[((b * 10 + idxs[bb]) << 4) + f];
    }
    __syncthreads();

    {
        const int bb = t >> 4, tg = t & 15;
        const float* w = W1 + (size_t)idxs[bb] * 8192;
        float r[16];
        #pragma unroll
        for (int k = 0; k < 16; ++k) r[k] = r16s[bb][k];
        for (int j = tg; j < 512; j += 16) {
            float a = B1[j];
            #pragma unroll
            for (int k = 0; k < 16; ++k) a = fmaf(r[k], w[k * 512 + j], a);
            h1s[bb][j] = fmaxf(a, 0.f);
        }
    }
    __syncthreads();

    {
        const int bb = t >> 4;
        const int o = ot * 64 + (t & 15) * 4;
        float4 bv = *(const float4*)(B2 + o);
        float a0 = bv.x, a1 = bv.y, a2 = bv.z, a3 = bv.w;
        #pragma unroll 4
        for (int k = 0; k < 512; ++k) {
            float hv = h1s[bb][k];
            float4 w0 = *(const float4*)(W2 + (size_t)k * 1024 + o);
            a0 = fmaf(hv, w0.x, a0); a1 = fmaf(hv, w0.y, a1);
            a2 = fmaf(hv, w0.z, a2); a3 = fmaf(hv, w0.w, a3);
        }
        float* hw = h2 + (size_t)(bt * 16 + bb) * 1024 + o;
        hw[0] = fmaxf(a0, 0.f); hw[1] = fmaxf(a1, 0.f);
        hw[2] = fmaxf(a2, 0.f); hw[3] = fmaxf(a3, 0.f);
    }
}

// ------- dec3: grid (13,32) = 416 blocks; 8 batches x 64 outs per block -------------
__global__ __launch_bounds__(256) void dec3_kernel(
    const float* __restrict__ h2, const float* __restrict__ W3,
    const float* __restrict__ B3, float* __restrict__ out)
{
    const int ot = blockIdx.x, bt = blockIdx.y, t = threadIdx.x;
    const int bb = bt * 8 + (t >> 5);
    const int o = ot * 64 + (t & 31) * 2;
    if (o >= 784) return;

    float a0 = B3[o], a1 = B3[o + 1];
    const float* hr = h2 + (size_t)bb * 1024;
    #pragma unroll 4
    for (int k = 0; k < 1024; ++k) {
        float hv = hr[k];
        const float* wp = W3 + (size_t)k * 784 + o;
        a0 = fmaf(hv, wp[0], a0);
        a1 = fmaf(hv, wp[1], a1);
    }
    float* ow = out + (size_t)bb * 784 + o;
    ow[0] = 1.f / (1.f + expf(-a0));
    ow[1] = 1.f / (1.f + expf(-a1));
}

extern "C" void kernel_launch(void* const* d_in, const int* in_sizes, int n_in,
                              void* d_out, int out_size, void* d_ws, size_t ws_size,
                              hipStream_t stream) {
    const float* x   = (const float*)d_in[0];
    const float* w1  = (const float*)d_in[1];
    const float* b1  = (const float*)d_in[2];
    const float* w2  = (const float*)d_in[3];
    const float* b2  = (const float*)d_in[4];
    const float* W   = (const float*)d_in[5];
    const float* dw1 = (const float*)d_in[6];
    const float* db1 = (const float*)d_in[7];
    const float* dw2 = (const float*)d_in[8];
    const float* db2 = (const float*)d_in[9];
    const float* dw3 = (const float*)d_in[10];
    const float* db3 = (const float*)d_in[11];

    float* ws   = (float*)d_ws;
    float* outp = (float*)d_out;

    const size_t avail = ws_size / 4;   // f32 slots
    int ks = 0;
    if      (avail >= 16498688ull + 7*2359296ull + 40960ull) ks = 7;
    else if (avail >= 16498688ull + 6*2359296ull + 40960ull) ks = 6;
    else if (avail >= 16498688ull + 4*2359296ull + 40960ull) ks = 4;
    else if (avail >= 16498688ull + 2*2359296ull + 40960ull) ks = 2;
    else if (avail >= 16498688ull + 1*2359296ull + 40960ull) ks = 1;

    if (ks > 0) {
        f16* Af = (f16*)ws;
        f16* Wf = (f16*)(ws + 13107200);
        f16* Wr = (f16*)(ws + 15761408);
        float* partial = ws + 16498688;
        float* vbuf = ws + 16498688 + (size_t)ks * 2359296;
        float* u  = ws;                       // overlays Af after conv2
        float* h2 = ws + 13107200;            // overlays Wf after conv2

        const int nwg = 72 * ks;              // 504 for ks=7; % 8 == 0
        const int spk = (648 + ks - 1) / ks;  // 93 for ks=7 (last slice guarded)
        conv1_kernel<<<dim3(17, 256), 256, 0, stream>>>(x, w1, b1, Af, nullptr, 0,
                                                        w2, Wf, W, Wr);
        conv2_async<<<nwg, 256, 0, stream>>>(Af, Wf, partial, ks, spk, nwg);
        reduce_kernel<<<256, 512, 0, stream>>>(partial, b2, u, ks);
        routing_kernel<<<1280, 256, 0, stream>>>(u, Wr, outp, vbuf);
        dec12_kernel<<<dim3(16, 16), 256, 0, stream>>>(outp, vbuf, dw1, db1, dw2, db2, h2);
        dec3_kernel<<<dim3(13, 32), 256, 0, stream>>>(h2, dw3, db3, outp + 2560);
    } else {
        // fallback: fp32 path (+ f16 routing W at tail of layout)
        float* c1   = ws;                     // 26214400
        float* c2   = c1 + 26214400;          // 2359296
        float* vbuf = c2 + 2359296;           // 40960
        float* h2   = vbuf + 40960;           // 262144
        f16* Wr     = (f16*)(h2 + 262144);    // 737280 slots
        f16* Wfscr  = (f16*)(h2 + 262144 + 368640);
        conv1_kernel<<<dim3(17, 256), 256, 0, stream>>>(x, w1, b1, nullptr, c1, 1,
                                                        w2, Wfscr, W, Wr);
        conv2_kernel<<<dim3(4, 64), 384, 0, stream>>>(c1, w2, b2, c2);
        squash_kernel<<<1152, 256, 0, stream>>>(c2);
        routing_kernel<<<1280, 256, 0, stream>>>(c2, Wr, outp, vbuf);
        dec12_kernel<<<dim3(16, 16), 256, 0, stream>>>(outp, vbuf, dw1, db1, dw2, db2, h2);
        dec3_kernel<<<dim3(13, 32), 256, 0, stream>>>(h2, dw3, db3, outp + 2560);
    }
}

// Round 20
// 437.515 us; speedup vs baseline: 1.1468x; 1.0054x over previous
//
#include <hip/hip_runtime.h>
#include <hip/hip_bf16.h>
#include <math.h>

typedef _Float16 f16;
typedef f16 f16x8 __attribute__((ext_vector_type(8)));
typedef f16 f16x4 __attribute__((ext_vector_type(4)));
typedef float f32x16 __attribute__((ext_vector_type(16)));

// ws layout (f32 slot offsets), fast path:
//   Af16 f16[26214400] @ 0            (13107200 slots)  [b][400pos][256ci]
//   Wf16 f16[5308416]  @ 13107200     (2654208 slots)   [81tap][256co][256ci]
//   Wr   f16[1474560]  @ 15761408     (737280 slots)    routing W in f16
//   partial f16 ks*2359296 @ 16498688 (ks*1179648 slots) layout [k][m][co]
//   vbuf f32 40960 @ 16498688 + ks*1179648
//   u  f32[2359296] @ 0        (overlays Af16 after conv2)
//   h2 f32[262144]  @ 13107200 (overlays Wf16 after conv2)
//
// LESSONS: (R9-R11) the f16-partial "write amplification" was a register
// spill from launch_bounds(256,3), NOT store coalescing (R11 refuted);
// keep (256,2), VGPR ~88-112. (R12/R14) grid balance near-integer blocks/CU.
// (R13/R14) async global_load_lds RING-3 + COUNTED vmcnt(6): conflicts 0.
// (R18) never drain vmcnt mid-loop (ring-2 regression 162->220us).
// (R15) routing: 2 samples/block, f16 uh/cl, f16x8 W loads.
// (R16/R17) tail: dec12 fusion, dec3 re-grid, wprep inside conv1, wide reduce.

// ------- fused conv1 + weight-prep launch: grid (17,256) --------------------------
__global__ __launch_bounds__(256) void conv1_kernel(
    const float* __restrict__ x, const float* __restrict__ w,
    const float* __restrict__ bias, f16* __restrict__ outh,
    float* __restrict__ outf, int mode,
    const float* __restrict__ w2, f16* __restrict__ Wf,
    const float* __restrict__ W, f16* __restrict__ Wr)
{
    __shared__ float smem[5184];
    const int t = threadIdx.x;

    if (blockIdx.x == 16) {
        // ---- weight prep path ----
        const int co = blockIdx.y;
        for (int chunk = 0; chunk < 4; ++chunk) {
            const int ci0 = chunk * 64;
            for (int i = t; i < 5184; i += 256)
                smem[i] = w2[(size_t)co * 20736 + ci0 * 81 + i];
            __syncthreads();
            const int ci = t & 63;
            for (int tap = t >> 6; tap < 81; tap += 4)
                Wf[((size_t)tap * 256 + co) * 256 + ci0 + ci] =
                    (f16)smem[ci * 81 + tap];
            __syncthreads();
        }
        const int base = co * 5760;
        for (int i = t; i < 5760; i += 256) Wr[base + i] = (f16)W[base + i];
        return;
    }

    // ---- conv1 path ----
    float* xs = smem;            // 784
    float* wt = smem + 784;      // 1296
    float* bs = smem + 2080;     // 16
    const int b = blockIdx.y;
    const int cg = blockIdx.x;

    for (int i = t; i < 784; i += 256) xs[i] = x[b * 784 + i];
    for (int i = t; i < 1296; i += 256) {
        int k = i >> 4, cc = i & 15;
        wt[i] = w[(cg * 16 + cc) * 81 + k];
    }
    if (t < 16) bs[t] = bias[cg * 16 + t];
    __syncthreads();

    if (t >= 200) return;
    const int pos = t * 2;
    const int oy = pos / 20, ox = pos % 20;
    float4 A0[4], A1[4];
    #pragma unroll
    for (int g = 0; g < 4; ++g) { A0[g] = make_float4(0,0,0,0); A1[g] = make_float4(0,0,0,0); }

    for (int ky = 0; ky < 9; ++ky) {
        const float* xr = &xs[(oy + ky) * 28 + ox];
        #pragma unroll
        for (int kx = 0; kx < 9; ++kx) {
            float x0 = xr[kx], x1 = xr[kx + 1];
            const float4* wp = (const float4*)&wt[(ky * 9 + kx) << 4];
            #pragma unroll
            for (int g = 0; g < 4; ++g) {
                float4 wv = wp[g];
                A0[g].x = fmaf(x0, wv.x, A0[g].x); A0[g].y = fmaf(x0, wv.y, A0[g].y);
                A0[g].z = fmaf(x0, wv.z, A0[g].z); A0[g].w = fmaf(x0, wv.w, A0[g].w);
                A1[g].x = fmaf(x1, wv.x, A1[g].x); A1[g].y = fmaf(x1, wv.y, A1[g].y);
                A1[g].z = fmaf(x1, wv.z, A1[g].z); A1[g].w = fmaf(x1, wv.w, A1[g].w);
            }
        }
    }

    float va[16], vb[16];
    #pragma unroll
    for (int g = 0; g < 4; ++g) {
        va[g*4+0] = fmaxf(A0[g].x + bs[g*4+0], 0.f);
        va[g*4+1] = fmaxf(A0[g].y + bs[g*4+1], 0.f);
        va[g*4+2] = fmaxf(A0[g].z + bs[g*4+2], 0.f);
        va[g*4+3] = fmaxf(A0[g].w + bs[g*4+3], 0.f);
        vb[g*4+0] = fmaxf(A1[g].x + bs[g*4+0], 0.f);
        vb[g*4+1] = fmaxf(A1[g].y + bs[g*4+1], 0.f);
        vb[g*4+2] = fmaxf(A1[g].z + bs[g*4+2], 0.f);
        vb[g*4+3] = fmaxf(A1[g].w + bs[g*4+3], 0.f);
    }

    if (mode == 0) {
        size_t base0 = ((size_t)b * 400 + pos) * 256 + cg * 16;
        f16x8 H;
        #pragma unroll
        for (int q = 0; q < 8; ++q) H[q] = (f16)va[q];
        *(f16x8*)(outh + base0) = H;
        #pragma unroll
        for (int q = 0; q < 8; ++q) H[q] = (f16)va[8+q];
        *(f16x8*)(outh + base0 + 8) = H;
        size_t base1 = base0 + 256;
        #pragma unroll
        for (int q = 0; q < 8; ++q) H[q] = (f16)vb[q];
        *(f16x8*)(outh + base1) = H;
        #pragma unroll
        for (int q = 0; q < 8; ++q) H[q] = (f16)vb[8+q];
        *(f16x8*)(outh + base1 + 8) = H;
    } else {
        #pragma unroll
        for (int q = 0; q < 16; ++q) {
            size_t base = (size_t)(b * 256 + cg * 16 + q) * 400 + pos;
            outf[base] = va[q]; outf[base + 1] = vb[q];
        }
    }
}

// ------- conv2: async global->LDS, ring-3, counted vmcnt(6), ks=7, f16 partial -----
#define GLOAD16(GSRC, LDST) \
    __builtin_amdgcn_global_load_lds( \
        (const __attribute__((address_space(1))) void*)(GSRC), \
        (__attribute__((address_space(3))) void*)(LDST), 16, 0, 0)

__global__ __launch_bounds__(256, 2) void conv2_async(
    const f16* __restrict__ A, const f16* __restrict__ B,
    f16* __restrict__ partial, int nslice, int spk, int nwg)
{
    const int cpx = nwg >> 3;
    const int wg = (blockIdx.x & 7) * cpx + (blockIdx.x >> 3);
    const int mblk = wg / nslice;
    const int kslice = wg % nslice;

    const int t = threadIdx.x;
    const int lane = t & 63, w = t >> 6;     // 4 waves
    const int wm = w >> 1, wn = w & 1;

    __shared__ f16 sA3[3][4096];   // 24 KB
    __shared__ f16 sB3[3][8192];   // 48 KB

    const f16* aBase[2];
    #pragma unroll
    for (int q = 0; q < 2; ++q) {
        int m = mblk * 128 + q * 64 + lane;
        int b_ = m / 36, s_ = m % 36;
        aBase[q] = A + b_ * 102400 + ((s_ / 6) * 40 + (s_ % 6) * 2) * 256 + w * 8;
    }
    const f16* bBase[4];
    #pragma unroll
    for (int q = 0; q < 4; ++q)
        bBase[q] = B + (q * 64 + lane) * 256 + w * 8;

    const int g0 = kslice * spk;
    const int len = min(spk, 648 - g0);

    auto issue = [&](int gstep, int buf) {
        const int tap = gstep >> 3;
        const int kc = (gstep & 7) << 5;
        const int ky = tap / 9, kx = tap - ky * 9;
        const int ao = (ky * 20 + kx) * 256 + kc;
        const int bo = tap * 65536 + kc;
        f16* la = &sA3[buf][w * 1024];
        f16* lb = &sB3[buf][w * 2048];
        GLOAD16(aBase[0] + ao, la);
        GLOAD16(aBase[1] + ao, la + 512);
        GLOAD16(bBase[0] + bo, lb);
        GLOAD16(bBase[1] + bo, lb + 512);
        GLOAD16(bBase[2] + bo, lb + 1024);
        GLOAD16(bBase[3] + bo, lb + 1536);
    };

    const int kh = lane >> 5;
    const int rArow = wm * 64 + (lane & 31);
    const int rBrow = wn * 128 + (lane & 31);
    int offA[2], offB[2];
    #pragma unroll
    for (int h = 0; h < 2; ++h) {
        offA[h] = ((h * 2 + kh) << 11) + rArow * 16;
        offB[h] = ((h * 2 + kh) << 12) + rBrow * 16;
    }

    f32x16 acc00 = {}, acc01 = {}, acc02 = {}, acc03 = {};
    f32x16 acc10 = {}, acc11 = {}, acc12 = {}, acc13 = {};

    issue(g0, 0);
    if (len > 1) issue(g0 + 1, 1);

    for (int s = 0; s < len; ++s) {
        const int buf = s % 3;
        if (s + 1 < len) { asm volatile("s_waitcnt vmcnt(6)" ::: "memory"); }
        else             { asm volatile("s_waitcnt vmcnt(0)" ::: "memory"); }
        __builtin_amdgcn_s_barrier();
        asm volatile("" ::: "memory");
        if (s + 2 < len) issue(g0 + s + 2, (s + 2) % 3);

        const char* baseA = (const char*)sA3 + buf * 8192;
        const char* baseB = (const char*)sB3 + buf * 16384;
        #pragma unroll
        for (int h = 0; h < 2; ++h) {
            f16x8 a0 = *(const f16x8*)(baseA + offA[h]);
            f16x8 a1 = *(const f16x8*)(baseA + offA[h] + 512);
            f16x8 b0 = *(const f16x8*)(baseB + offB[h]);
            f16x8 b1 = *(const f16x8*)(baseB + offB[h] + 512);
            f16x8 b2 = *(const f16x8*)(baseB + offB[h] + 1024);
            f16x8 b3 = *(const f16x8*)(baseB + offB[h] + 1536);
            acc00 = __builtin_amdgcn_mfma_f32_32x32x16_f16(a0, b0, acc00, 0, 0, 0);
            acc01 = __builtin_amdgcn_mfma_f32_32x32x16_f16(a0, b1, acc01, 0, 0, 0);
            acc02 = __builtin_amdgcn_mfma_f32_32x32x16_f16(a0, b2, acc02, 0, 0, 0);
            acc03 = __builtin_amdgcn_mfma_f32_32x32x16_f16(a0, b3, acc03, 0, 0, 0);
            acc10 = __builtin_amdgcn_mfma_f32_32x32x16_f16(a1, b0, acc10, 0, 0, 0);
            acc11 = __builtin_amdgcn_mfma_f32_32x32x16_f16(a1, b1, acc11, 0, 0, 0);
            acc12 = __builtin_amdgcn_mfma_f32_32x32x16_f16(a1, b2, acc12, 0, 0, 0);
            acc13 = __builtin_amdgcn_mfma_f32_32x32x16_f16(a1, b3, acc13, 0, 0, 0);
        }
    }

    // epilogue: partial[kslice][m][co] f16 scalar stores
    // (lanes 0..31 -> 64B contiguous; R11 refuted the non-coalescing theory)
    f16* pp = partial + (size_t)kslice * 2359296;
    const int colb = wn * 128 + (lane & 31);
    const int rowb = mblk * 128 + wm * 64 + 4 * (lane >> 5);
    #pragma unroll
    for (int a = 0; a < 2; ++a) {
        #pragma unroll
        for (int nf = 0; nf < 4; ++nf) {
            const f32x16 v = (a == 0)
                ? (nf == 0 ? acc00 : nf == 1 ? acc01 : nf == 2 ? acc02 : acc03)
                : (nf == 0 ? acc10 : nf == 1 ? acc11 : nf == 2 ? acc12 : acc13);
            const int col = colb + nf * 32;
            const int rb = rowb + a * 32;
            #pragma unroll
            for (int r = 0; r < 16; ++r) {
                int row = rb + (r & 3) + 8 * (r >> 2);
                pp[(size_t)row * 256 + col] = (f16)v[r];
            }
        }
    }
}

// ------- reduce: 512 threads; f16 partial[k][m][co] + bias+relu+squash -> u ----------
__global__ __launch_bounds__(512) void reduce_kernel(
    const f16* __restrict__ partial, const float* __restrict__ bias,
    float* __restrict__ u, int ks)
{
    const int b = blockIdx.x, t = threadIdx.x;
    __shared__ float ld[36 * 260];
    const int cog = t & 63;
    const int srow = t >> 6;
    const float4 bv = *(const float4*)(bias + cog * 4);
    #pragma unroll
    for (int q = 0; q < 5; ++q) {
        const int s = srow + q * 8;
        if (s < 36) {
            const size_t idx = ((size_t)(b * 36 + s)) * 256 + cog * 4;
            float a0 = bv.x, a1 = bv.y, a2 = bv.z, a3 = bv.w;
            for (int k = 0; k < ks; ++k) {
                f16x4 p = *(const f16x4*)(partial + (size_t)k * 2359296 + idx);
                a0 += (float)p[0]; a1 += (float)p[1];
                a2 += (float)p[2]; a3 += (float)p[3];
            }
            float4 a = make_float4(fmaxf(a0, 0.f), fmaxf(a1, 0.f),
                                   fmaxf(a2, 0.f), fmaxf(a3, 0.f));
            *(float4*)&ld[s * 260 + cog * 4] = a;
        }
    }
    __syncthreads();
    for (int n = t; n < 1152; n += 512) {
        const int f0 = n * 8;
        float vals[8]; float sq = 0.f;
        int co = f0 / 36;
        int si = f0 - co * 36;
        #pragma unroll
        for (int d = 0; d < 8; ++d) {
            float v = ld[si * 260 + co];
            vals[d] = v; sq += v * v;
            if (++si == 36) { si = 0; ++co; }
        }
        float scale = (sq / (1.f + sq)) / sqrtf(sq + 1e-8f);
        #pragma unroll
        for (int d = 0; d < 8; ++d) u[(size_t)b * 9216 + f0 + d] = vals[d] * scale;
    }
}

// ---------------- OLD fallback conv2 (fp32) + squash ----------------
#define C2_CHUNK 2
__global__ __launch_bounds__(384) void conv2_kernel(
    const float* __restrict__ in, const float* __restrict__ w,
    const float* __restrict__ bias, float* __restrict__ out)
{
    const int bg = blockIdx.y;
    const int ct = blockIdx.x;
    const int t = threadIdx.x;

    __shared__ float wl[C2_CHUNK][81][64];
    __shared__ float il[C2_CHUNK][4][20][24];

    const int cg = t & 15;
    const int slot = t >> 4;
    const int bb = slot / 6;
    const int oy = slot % 6;

    float4 acc[6];
    #pragma unroll
    for (int i = 0; i < 6; ++i) acc[i] = make_float4(0,0,0,0);

    for (int cc0 = 0; cc0 < 256; cc0 += C2_CHUNK) {
        for (int idx = t; idx < C2_CHUNK * 5184; idx += 384) {
            int ci = idx / 5184;
            int r = idx - ci * 5184;
            int kk = r >> 6;
            int co = r & 63;
            wl[ci][kk][co] = w[(size_t)(ct * 64 + co) * 20736 + (cc0 + ci) * 81 + kk];
        }
        for (int idx = t; idx < C2_CHUNK * 1600; idx += 384) {
            int ci = idx / 1600;
            int r = idx - ci * 1600;
            int bb2 = r / 400;
            int p = r - bb2 * 400;
            int y = p / 20;
            int xx = p - y * 20;
            il[ci][bb2][y][(xx & 1) * 12 + (xx >> 1)] =
                in[(size_t)((bg * 4 + bb2) * 256 + cc0 + ci) * 400 + p];
        }
        __syncthreads();

        #pragma unroll
        for (int ci = 0; ci < C2_CHUNK; ++ci) {
            for (int ky = 0; ky < 9; ++ky) {
                const int y = oy * 2 + ky;
                const float4* rowp = (const float4*)&il[ci][bb][y][0];
                float a[24];
                #pragma unroll
                for (int q = 0; q < 6; ++q) *(((float4*)a) + q) = rowp[q];
                #pragma unroll
                for (int kx = 0; kx < 9; ++kx) {
                    const int k = ky * 9 + kx;
                    float4 wv = *(const float4*)&wl[ci][k][cg * 4];
                    const int base = (kx & 1) ? (12 + (kx >> 1)) : (kx >> 1);
                    #pragma unroll
                    for (int ox = 0; ox < 6; ++ox) {
                        float av = a[base + ox];
                        acc[ox].x = fmaf(av, wv.x, acc[ox].x);
                        acc[ox].y = fmaf(av, wv.y, acc[ox].y);
                        acc[ox].z = fmaf(av, wv.z, acc[ox].z);
                        acc[ox].w = fmaf(av, wv.w, acc[ox].w);
                    }
                }
            }
        }
        __syncthreads();
    }

    const int b = bg * 4 + bb;
    const int c0 = ct * 64 + cg * 4;
    float4 bv = *(const float4*)&bias[c0];
    #pragma unroll
    for (int ox = 0; ox < 6; ++ox) {
        int sdx = oy * 6 + ox;
        size_t ob = (size_t)b * 9216 + sdx;
        out[ob + (size_t)(c0 + 0) * 36] = fmaxf(acc[ox].x + bv.x, 0.f);
        out[ob + (size_t)(c0 + 1) * 36] = fmaxf(acc[ox].y + bv.y, 0.f);
        out[ob + (size_t)(c0 + 2) * 36] = fmaxf(acc[ox].z + bv.z, 0.f);
        out[ob + (size_t)(c0 + 3) * 36] = fmaxf(acc[ox].w + bv.w, 0.f);
    }
}

__global__ __launch_bounds__(256) void squash_kernel(float* __restrict__ h)
{
    const int cap = blockIdx.x * 256 + threadIdx.x;
    float4* p = (float4*)(h + (size_t)cap * 8);
    float4 v0 = p[0], v1 = p[1];
    float sq = v0.x*v0.x + v0.y*v0.y + v0.z*v0.z + v0.w*v0.w
             + v1.x*v1.x + v1.y*v1.y + v1.z*v1.z + v1.w*v1.w;
    float scale = (sq / (1.f + sq)) / sqrtf(sq + 1e-8f);
    v0.x *= scale; v0.y *= scale; v0.z *= scale; v0.w *= scale;
    v1.x *= scale; v1.y *= scale; v1.z *= scale; v1.w *= scale;
    p[0] = v0; p[1] = v1;
}

// ------- fused u_hat + routing: 2 samples/block share Wc; f16 uh/cl; f16x8 W loads ----
__global__ __launch_bounds__(256) void routing_kernel(
    const float* __restrict__ u, const f16* __restrict__ Wr,
    float* __restrict__ cp_out, float* __restrict__ vbuf)
{
    const int wg = ((blockIdx.x & 7) * 160) + (blockIdx.x >> 3);
    const int c = wg >> 7;
    const int bp = wg & 127;
    const int b0 = bp * 2, b1 = b0 + 1;
    const int t = threadIdx.x;
    const int lane = t & 63, wid = t >> 6;

    __shared__ f16 uhh[2 * 1152 * 16];   // 73728 B
    __shared__ f16 clh[2 * 1152];        // 4608 B
    __shared__ float red[512];           // 2048 B
    __shared__ float rtmp[16];
    __shared__ float vv[2][16];

    {
        const int fg = t & 1;
        const int ng = t >> 1;
        const f16* Wc = Wr + (size_t)c * 147456;
        const float* ub0 = u + (size_t)b0 * 9216;
        const float* ub1 = u + (size_t)b1 * 9216;
        for (int j = 0; j < 9; ++j) {
            const int n = ng + (j << 7);
            const f16* wn = Wc + n * 128 + fg * 8;
            float4 u00 = *(const float4*)(ub0 + n * 8);
            float4 u01 = *(const float4*)(ub0 + n * 8 + 4);
            float4 u10 = *(const float4*)(ub1 + n * 8);
            float4 u11 = *(const float4*)(ub1 + n * 8 + 4);
            float ud0[8] = {u00.x,u00.y,u00.z,u00.w,u01.x,u01.y,u01.z,u01.w};
            float ud1[8] = {u10.x,u10.y,u10.z,u10.w,u11.x,u11.y,u11.z,u11.w};
            float a0[8] = {0,0,0,0,0,0,0,0}, a1[8] = {0,0,0,0,0,0,0,0};
            #pragma unroll
            for (int d = 0; d < 8; ++d) {
                f16x8 w8 = *(const f16x8*)(wn + (d << 4));
                #pragma unroll
                for (int e = 0; e < 8; ++e) {
                    float wf = (float)w8[e];
                    a0[e] = fmaf(ud0[d], wf, a0[e]);
                    a1[e] = fmaf(ud1[d], wf, a1[e]);
                }
            }
            f16x8 h0, h1;
            #pragma unroll
            for (int e = 0; e < 8; ++e) { h0[e] = (f16)a0[e]; h1[e] = (f16)a1[e]; }
            *(f16x8*)&uhh[(n << 4) + (fg << 3)] = h0;
            *(f16x8*)&uhh[18432 + (n << 4) + (fg << 3)] = h1;
        }
    }
    __syncthreads();

    float blr0[5] = {0,0,0,0,0}, blr1[5] = {0,0,0,0,0};
    const int nown = (t < 128) ? 5 : 4;

    for (int it = 0; it < 3; ++it) {
        float m0 = -1e30f, m1 = -1e30f;
        #pragma unroll
        for (int k = 0; k < 5; ++k) if (k < nown) {
            m0 = fmaxf(m0, blr0[k]); m1 = fmaxf(m1, blr1[k]);
        }
        #pragma unroll
        for (int o = 32; o > 0; o >>= 1) {
            m0 = fmaxf(m0, __shfl_xor(m0, o));
            m1 = fmaxf(m1, __shfl_xor(m1, o));
        }
        if (lane == 0) { rtmp[wid] = m0; rtmp[4 + wid] = m1; }
        __syncthreads();
        m0 = fmaxf(fmaxf(rtmp[0], rtmp[1]), fmaxf(rtmp[2], rtmp[3]));
        m1 = fmaxf(fmaxf(rtmp[4], rtmp[5]), fmaxf(rtmp[6], rtmp[7]));

        float s0 = 0.f, s1 = 0.f;
        #pragma unroll
        for (int k = 0; k < 5; ++k) if (k < nown) {
            float e0 = __expf(blr0[k] - m0);
            float e1 = __expf(blr1[k] - m1);
            clh[t + (k << 8)] = (f16)e0;
            clh[1152 + t + (k << 8)] = (f16)e1;
            s0 += e0; s1 += e1;
        }
        #pragma unroll
        for (int o = 32; o > 0; o >>= 1) {
            s0 += __shfl_xor(s0, o);
            s1 += __shfl_xor(s1, o);
        }
        if (lane == 0) { rtmp[8 + wid] = s0; rtmp[12 + wid] = s1; }
        __syncthreads();
        const float inv0 = 1.f / (rtmp[8] + rtmp[9] + rtmp[10] + rtmp[11]);
        const float inv1 = 1.f / (rtmp[12] + rtmp[13] + rtmp[14] + rtmp[15]);

        const int f = t & 15, g = t >> 4;
        float sa0 = 0.f, sa1 = 0.f;
        for (int n = g; n < 1152; n += 16) {
            sa0 = fmaf((float)clh[n], (float)uhh[(n << 4) + f], sa0);
            sa1 = fmaf((float)clh[1152 + n], (float)uhh[18432 + (n << 4) + f], sa1);
        }
        red[(g << 4) + f] = sa0;
        red[256 + (g << 4) + f] = sa1;
        __syncthreads();
        if (t < 32) {
            const int s = t >> 4;
            const int ff = t & 15;
            float sv = 0.f;
            #pragma unroll
            for (int gg = 0; gg < 16; ++gg) sv += red[s * 256 + (gg << 4) + ff];
            sv *= (s == 0) ? inv0 : inv1;
            float sq = sv * sv;
            #pragma unroll
            for (int o = 8; o > 0; o >>= 1) sq += __shfl_xor(sq, o);
            float scale = (sq / (1.f + sq)) / sqrtf(sq + 1e-8f);
            vv[s][ff] = sv * scale;
        }
        __syncthreads();

        if (it < 2) {
            float v0[16], v1[16];
            #pragma unroll
            for (int e = 0; e < 16; ++e) { v0[e] = vv[0][e]; v1[e] = vv[1][e]; }
            #pragma unroll
            for (int k = 0; k < 5; ++k) if (k < nown) {
                const int n = t + (k << 8);
                f16x8 q0 = *(const f16x8*)&uhh[n << 4];
                f16x8 q1 = *(const f16x8*)&uhh[(n << 4) + 8];
                f16x8 r0 = *(const f16x8*)&uhh[18432 + (n << 4)];
                f16x8 r1 = *(const f16x8*)&uhh[18432 + (n << 4) + 8];
                float d0 = 0.f, d1 = 0.f;
                #pragma unroll
                for (int e = 0; e < 8; ++e) {
                    d0 = fmaf((float)q0[e], v0[e], d0);
                    d0 = fmaf((float)q1[e], v0[8 + e], d0);
                    d1 = fmaf((float)r0[e], v1[e], d1);
                    d1 = fmaf((float)r1[e], v1[8 + e], d1);
                }
                blr0[k] += d0; blr1[k] += d1;
            }
        }
    }

    if (t < 32) {
        const int s = t >> 4;
        const int ff = t & 15;
        float v_ = vv[s][ff];
        float s2 = v_ * v_;
        #pragma unroll
        for (int o = 8; o > 0; o >>= 1) s2 += __shfl_xor(s2, o);
        const int b = (s == 0) ? b0 : b1;
        if (ff == 0) cp_out[b * 10 + c] = sqrtf(s2 + 1e-8f);
        vbuf[((b * 10 + c) << 4) + ff] = v_;
    }
}

// ------- dec12: fused argmax+mask + layer1 (LDS) + layer2 GEMM ----------------------
__global__ __launch_bounds__(256) void dec12_kernel(
    const float* __restrict__ cp, const float* __restrict__ vbuf,
    const float* __restrict__ W1, const float* __restrict__ B1,
    const float* __restrict__ W2, const float* __restrict__ B2,
    float* __restrict__ h2)
{
    const int ot = blockIdx.x, bt = blockIdx.y, t = threadIdx.x;
    __shared__ float h1s[16][516];   // 33KB, padded
    __shared__ float r16s[16][16];
    __shared__ int idxs[16];

    if (t < 16) {
        const int b = bt * 16 + t;
        float best = cp[b * 10];
        int idx = 0;
        #pragma unroll
        for (int cc = 1; cc < 10; ++cc) {
            float p = cp[b * 10 + cc];
            if (p > best) { best = p; idx = cc; }
        }
        idxs[t] = idx;
    }
    __syncthreads();
    {
        const int bb = t >> 4, f = t & 15;
        const int b = bt * 16 + bb;
        r16s[bb][f] = vbuf[((b * 10 + idxs[bb]) << 4) + f];
    }
    __syncthreads();

    {
        const int bb = t >> 4, tg = t & 15;
        const float* w = W1 + (size_t)idxs[bb] * 8192;
        float r[16];
        #pragma unroll
        for (int k = 0; k < 16; ++k) r[k] = r16s[bb][k];
        for (int j = tg; j < 512; j += 16) {
            float a = B1[j];
            #pragma unroll
            for (int k = 0; k < 16; ++k) a = fmaf(r[k], w[k * 512 + j], a);
            h1s[bb][j] = fmaxf(a, 0.f);
        }
    }
    __syncthreads();

    {
        const int bb = t >> 4;
        const int o = ot * 64 + (t & 15) * 4;
        float4 bv = *(const float4*)(B2 + o);
        float a0 = bv.x, a1 = bv.y, a2 = bv.z, a3 = bv.w;
        #pragma unroll 4
        for (int k = 0; k < 512; ++k) {
            float hv = h1s[bb][k];
            float4 w0 = *(const float4*)(W2 + (size_t)k * 1024 + o);
            a0 = fmaf(hv, w0.x, a0); a1 = fmaf(hv, w0.y, a1);
            a2 = fmaf(hv, w0.z, a2); a3 = fmaf(hv, w0.w, a3);
        }
        float* hw = h2 + (size_t)(bt * 16 + bb) * 1024 + o;
        hw[0] = fmaxf(a0, 0.f); hw[1] = fmaxf(a1, 0.f);
        hw[2] = fmaxf(a2, 0.f); hw[3] = fmaxf(a3, 0.f);
    }
}

// ------- dec3: grid (13,32) = 416 blocks; 8 batches x 64 outs per block -------------
__global__ __launch_bounds__(256) void dec3_kernel(
    const float* __restrict__ h2, const float* __restrict__ W3,
    const float* __restrict__ B3, float* __restrict__ out)
{
    const int ot = blockIdx.x, bt = blockIdx.y, t = threadIdx.x;
    const int bb = bt * 8 + (t >> 5);
    const int o = ot * 64 + (t & 31) * 2;
    if (o >= 784) return;

    float a0 = B3[o], a1 = B3[o + 1];
    const float* hr = h2 + (size_t)bb * 1024;
    #pragma unroll 4
    for (int k = 0; k < 1024; ++k) {
        float hv = hr[k];
        const float* wp = W3 + (size_t)k * 784 + o;
        a0 = fmaf(hv, wp[0], a0);
        a1 = fmaf(hv, wp[1], a1);
    }
    float* ow = out + (size_t)bb * 784 + o;
    ow[0] = 1.f / (1.f + expf(-a0));
    ow[1] = 1.f / (1.f + expf(-a1));
}

extern "C" void kernel_launch(void* const* d_in, const int* in_sizes, int n_in,
                              void* d_out, int out_size, void* d_ws, size_t ws_size,
                              hipStream_t stream) {
    const float* x   = (const float*)d_in[0];
    const float* w1  = (const float*)d_in[1];
    const float* b1  = (const float*)d_in[2];
    const float* w2  = (const float*)d_in[3];
    const float* b2  = (const float*)d_in[4];
    const float* W   = (const float*)d_in[5];
    const float* dw1 = (const float*)d_in[6];
    const float* db1 = (const float*)d_in[7];
    const float* dw2 = (const float*)d_in[8];
    const float* db2 = (const float*)d_in[9];
    const float* dw3 = (const float*)d_in[10];
    const float* db3 = (const float*)d_in[11];

    float* ws   = (float*)d_ws;
    float* outp = (float*)d_out;

    const size_t avail = ws_size / 4;   // f32 slots
    // f16 partial: ks*1179648 slots
    int ks = 0;
    if      (avail >= 16498688ull + 7*1179648ull + 40960ull) ks = 7;
    else if (avail >= 16498688ull + 6*1179648ull + 40960ull) ks = 6;
    else if (avail >= 16498688ull + 4*1179648ull + 40960ull) ks = 4;
    else if (avail >= 16498688ull + 2*1179648ull + 40960ull) ks = 2;
    else if (avail >= 16498688ull + 1*1179648ull + 40960ull) ks = 1;

    if (ks > 0) {
        f16* Af = (f16*)ws;
        f16* Wf = (f16*)(ws + 13107200);
        f16* Wr = (f16*)(ws + 15761408);
        f16* partial = (f16*)(ws + 16498688);
        float* vbuf = ws + 16498688 + (size_t)ks * 1179648;
        float* u  = ws;                       // overlays Af after conv2
        float* h2 = ws + 13107200;            // overlays Wf after conv2

        const int nwg = 72 * ks;              // 504 for ks=7; % 8 == 0
        const int spk = (648 + ks - 1) / ks;  // 93 for ks=7 (last slice guarded)
        conv1_kernel<<<dim3(17, 256), 256, 0, stream>>>(x, w1, b1, Af, nullptr, 0,
                                                        w2, Wf, W, Wr);
        conv2_async<<<nwg, 256, 0, stream>>>(Af, Wf, partial, ks, spk, nwg);
        reduce_kernel<<<256, 512, 0, stream>>>(partial, b2, u, ks);
        routing_kernel<<<1280, 256, 0, stream>>>(u, Wr, outp, vbuf);
        dec12_kernel<<<dim3(16, 16), 256, 0, stream>>>(outp, vbuf, dw1, db1, dw2, db2, h2);
        dec3_kernel<<<dim3(13, 32), 256, 0, stream>>>(h2, dw3, db3, outp + 2560);
    } else {
        // fallback: fp32 path (+ f16 routing W at tail of layout)
        float* c1   = ws;                     // 26214400
        float* c2   = c1 + 26214400;          // 2359296
        float* vbuf = c2 + 2359296;           // 40960
        float* h2   = vbuf + 40960;           // 262144
        f16* Wr     = (f16*)(h2 + 262144);    // 737280 slots
        f16* Wfscr  = (f16*)(h2 + 262144 + 368640);
        conv1_kernel<<<dim3(17, 256), 256, 0, stream>>>(x, w1, b1, nullptr, c1, 1,
                                                        w2, Wfscr, W, Wr);
        conv2_kernel<<<dim3(4, 64), 384, 0, stream>>>(c1, w2, b2, c2);
        squash_kernel<<<1152, 256, 0, stream>>>(c2);
        routing_kernel<<<1280, 256, 0, stream>>>(c2, Wr, outp, vbuf);
        dec12_kernel<<<dim3(16, 16), 256, 0, stream>>>(outp, vbuf, dw1, db1, dw2, db2, h2);
        dec3_kernel<<<dim3(13, 32), 256, 0, stream>>>(h2, dw3, db3, outp + 2560);
    }
}